// Round 3
// baseline (216.100 us; speedup 1.0000x reference)
//
#include <hip/hip_runtime.h>
#include <hip/hip_bf16.h>

#define B_ 2
#define T_ 2048
#define C_ 1024
#define NH_ 16
#define NKV_ 4
#define HD_ 64
#define NQKV_ 1536           // (NH + 2*NKV) * HD
#define M_ 4096              // B_ * T_

typedef __attribute__((ext_vector_type(8))) __bf16 bf16x8;
typedef __attribute__((ext_vector_type(4))) __bf16 bf16x4;
typedef __attribute__((ext_vector_type(4))) float f32x4;
typedef __attribute__((ext_vector_type(4))) unsigned int u32x4;

// ---------------- cast x (fp32 -> bf16), 4 elems/thread ----------------
__global__ __launch_bounds__(256) void cast_x_kernel(const float* __restrict__ in,
                                                     __bf16* __restrict__ out) {
  const int i = blockIdx.x * 256 + threadIdx.x;
  const float4 v = ((const float4*)in)[i];
  bf16x4 o;
  o.x = (__bf16)v.x; o.y = (__bf16)v.y; o.z = (__bf16)v.z; o.w = (__bf16)v.w;
  ((bf16x4*)out)[i] = o;
}

// ---------- transpose + cast: in [K][N] fp32 -> out [N][K] bf16 ----------
__global__ __launch_bounds__(256) void transpose_cast_kernel(const float* __restrict__ in,
                                                             __bf16* __restrict__ out,
                                                             int K, int N) {
  __shared__ __bf16 tile[64][72];  // [n_local][k_local], padded
  const int n0 = blockIdx.x * 64, k0 = blockIdx.y * 64;
  const int tid = threadIdx.x;
  const int tr = tid >> 4, tc4 = (tid & 15) << 2;
  #pragma unroll
  for (int p = 0; p < 4; ++p) {
    const int k = k0 + p * 16 + tr;
    const float4 v = *(const float4*)&in[(size_t)k * N + n0 + tc4];
    tile[tc4 + 0][p * 16 + tr] = (__bf16)v.x;
    tile[tc4 + 1][p * 16 + tr] = (__bf16)v.y;
    tile[tc4 + 2][p * 16 + tr] = (__bf16)v.z;
    tile[tc4 + 3][p * 16 + tr] = (__bf16)v.w;
  }
  __syncthreads();
  #pragma unroll
  for (int p = 0; p < 4; ++p) {
    const int n = n0 + p * 16 + tr;
    bf16x4 o;
    o.x = tile[p * 16 + tr][tc4 + 0];
    o.y = tile[p * 16 + tr][tc4 + 1];
    o.z = tile[p * 16 + tr][tc4 + 2];
    o.w = tile[p * 16 + tr][tc4 + 3];
    *(bf16x4*)&out[(size_t)n * K + k0 + tc4] = o;
  }
}

// ---------------- RoPE cos/sin tables [T][32] fp32 ----------------
__global__ __launch_bounds__(256) void rope_table_kernel(float* __restrict__ cosT,
                                                         float* __restrict__ sinT) {
  const int idx = blockIdx.x * 256 + threadIdx.x;  // T*32 total
  const int t = idx >> 5, i = idx & 31;
  const float inv = powf(10000.0f, -(float)i * (1.0f / 32.0f));
  const float ang = (float)t * inv;
  cosT[idx] = cosf(ang);
  sinT[idx] = sinf(ang);
}

// ------- bf16 TN GEMM: A[M][K] * Bt[N][K]^T -> C[M][N] fp32 -------
// 128x128 tile, BK=64, 4 waves (2x2), reg-staged LDS with XOR swizzle.
__global__ __launch_bounds__(256) void gemm_tn_kernel(const __bf16* __restrict__ A,
                                                      const __bf16* __restrict__ Bt,
                                                      float* __restrict__ C, int N, int K) {
  __shared__ __align__(16) __bf16 lA[128 * 64];
  __shared__ __align__(16) __bf16 lB[128 * 64];
  const int tid = threadIdx.x;
  const int lane = tid & 63;
  const int wave = tid >> 6;
  const int wr = wave >> 1, wc = wave & 1;
  const int m0 = blockIdx.y * 128, n0 = blockIdx.x * 128;
  const int srow = tid >> 3, kc = tid & 7;  // staging: 8 threads/row, 16B chunks
  const int r16 = lane & 15, g = lane >> 4;
  f32x4 acc[4][4] = {};
  for (int k0 = 0; k0 < K; k0 += 64) {
    u32x4 ra[4], rb[4];
    #pragma unroll
    for (int p = 0; p < 4; ++p) {
      const int row = p * 32 + srow;
      ra[p] = *(const u32x4*)&A[(size_t)(m0 + row) * K + k0 + kc * 8];
      rb[p] = *(const u32x4*)&Bt[(size_t)(n0 + row) * K + k0 + kc * 8];
    }
    __syncthreads();  // prior iter's ds_reads done before overwrite
    #pragma unroll
    for (int p = 0; p < 4; ++p) {
      const int row = p * 32 + srow;
      const int sw = kc ^ (row & 7);  // bank-conflict swizzle (G4)
      *(u32x4*)&lA[row * 64 + sw * 8] = ra[p];
      *(u32x4*)&lB[row * 64 + sw * 8] = rb[p];
    }
    __syncthreads();
    #pragma unroll
    for (int ks = 0; ks < 64; ks += 32) {
      bf16x8 af[4], bfr[4];
      const int kch = (ks >> 3) + g;
      #pragma unroll
      for (int mi = 0; mi < 4; ++mi) {
        const int row = wr * 64 + mi * 16 + r16;
        af[mi] = *(const bf16x8*)&lA[row * 64 + (kch ^ (row & 7)) * 8];
      }
      #pragma unroll
      for (int ni = 0; ni < 4; ++ni) {
        const int row = wc * 64 + ni * 16 + r16;
        bfr[ni] = *(const bf16x8*)&lB[row * 64 + (kch ^ (row & 7)) * 8];
      }
      #pragma unroll
      for (int mi = 0; mi < 4; ++mi)
        #pragma unroll
        for (int ni = 0; ni < 4; ++ni)
          acc[mi][ni] = __builtin_amdgcn_mfma_f32_16x16x32_bf16(af[mi], bfr[ni], acc[mi][ni], 0, 0, 0);
    }
  }
  // epilogue: D layout col=lane&15, row=(lane>>4)*4+j
  #pragma unroll
  for (int mi = 0; mi < 4; ++mi) {
    const int r0 = m0 + wr * 64 + mi * 16 + g * 4;
    #pragma unroll
    for (int ni = 0; ni < 4; ++ni) {
      const int c = n0 + wc * 64 + ni * 16 + r16;
      #pragma unroll
      for (int j = 0; j < 4; ++j)
        C[(size_t)(r0 + j) * N + c] = acc[mi][ni][j];
    }
  }
}

// ---- RoPE on q,k (from fp32 qkv) -> Q[b][h][t][d], K[b][kvh][t][d] bf16 ----
// Q is additionally pre-scaled by 1/8 * log2(e) (softmax runs in exp2 domain).
__global__ __launch_bounds__(256) void rope_qk_kernel(const float* __restrict__ qkv,
                                                      const float* __restrict__ cosT,
                                                      const float* __restrict__ sinT,
                                                      __bf16* __restrict__ Q,
                                                      __bf16* __restrict__ Kb) {
  const int idx = blockIdx.x * 256 + threadIdx.x;  // M_*(NH+NKV)*32 total
  const int i = idx & 31;
  const int rest = idx >> 5;
  const int head = rest % (NH_ + NKV_);
  const int row = rest / (NH_ + NKV_);
  const int b = row >> 11, t = row & 2047;
  const float c = cosT[t * 32 + i], s = sinT[t * 32 + i];
  if (head < NH_) {
    const float* p = &qkv[(size_t)row * NQKV_ + head * HD_ + 2 * i];
    const float o1 = p[0] * c - p[1] * s;
    const float o2 = p[0] * s + p[1] * c;
    __bf16* q = &Q[(((size_t)b * NH_ + head) * T_ + t) * HD_ + 2 * i];
    const float qs = 0.125f * 1.44269504f;
    q[0] = (__bf16)(o1 * qs); q[1] = (__bf16)(o2 * qs);
  } else {
    const int kh = head - NH_;
    const float* p = &qkv[(size_t)row * NQKV_ + NH_ * HD_ + kh * HD_ + 2 * i];
    const float o1 = p[0] * c - p[1] * s;
    const float o2 = p[0] * s + p[1] * c;
    __bf16* k = &Kb[(((size_t)b * NKV_ + kh) * T_ + t) * HD_ + 2 * i];
    k[0] = (__bf16)o1; k[1] = (__bf16)o2;
  }
}

// ---- V transpose: qkv v-part -> Vt[b][kvh][d][t] bf16 (LDS tiled) ----
__global__ __launch_bounds__(256) void v_transpose_kernel(const float* __restrict__ qkv,
                                                          __bf16* __restrict__ Vt) {
  __shared__ __bf16 tile[64][72];  // [d][t_local], padded
  const int blk = blockIdx.x;      // B*NKV*(T/64)
  const int t0 = (blk & 31) * 64;
  const int kvh = (blk >> 5) & 3;
  const int b = blk >> 7;
  const int tid = threadIdx.x;
  const int tr = tid >> 4, c4 = (tid & 15) << 2;
  #pragma unroll
  for (int p = 0; p < 4; ++p) {
    const int t = t0 + p * 16 + tr;
    const float4 v = *(const float4*)&qkv[(size_t)(b * T_ + t) * NQKV_ + (NH_ + NKV_) * HD_ + kvh * HD_ + c4];
    tile[c4 + 0][p * 16 + tr] = (__bf16)v.x;
    tile[c4 + 1][p * 16 + tr] = (__bf16)v.y;
    tile[c4 + 2][p * 16 + tr] = (__bf16)v.z;
    tile[c4 + 3][p * 16 + tr] = (__bf16)v.w;
  }
  __syncthreads();
  #pragma unroll
  for (int p = 0; p < 4; ++p) {
    const int d = p * 16 + tr;
    bf16x4 o;
    o.x = tile[d][c4 + 0]; o.y = tile[d][c4 + 1];
    o.z = tile[d][c4 + 2]; o.w = tile[d][c4 + 3];
    *(bf16x4*)&Vt[(((size_t)b * NKV_ + kvh) * HD_ + d) * T_ + t0 + c4] = o;
  }
}

// ---- flash attention: 4 waves/block, QBLK=64 (16 q-rows/wave), KVBLK=64 ----
// Balanced grid (longest q-tiles dispatched first), K/V prefetch into regs,
// exp2-domain softmax with deferred-max rescale (THR=8 log2 units).
__global__ __launch_bounds__(256) void attn_kernel(const __bf16* __restrict__ Q,
                                                   const __bf16* __restrict__ Kb,
                                                   const __bf16* __restrict__ Vt,
                                                   __bf16* __restrict__ Y) {
  __shared__ __align__(16) __bf16 lK[64 * 64];      // [kv][d], swizzled
  __shared__ __align__(16) __bf16 lV[64 * 64];      // [d][kv], swizzled
  __shared__ __align__(16) __bf16 pP[4][16 * 64];   // per-wave [q][kv], swizzled
  const int tid = threadIdx.x;
  const int lane = tid & 63, wave = tid >> 6;
  const int r16 = lane & 15, g = lane >> 4;
  const int qi = 31 - blockIdx.x;                   // longest-first dispatch
  const int bh = blockIdx.y;
  const int b = bh >> 4, h = bh & 15;
  const int kvh = h >> 2;  // GQA rep = 4
  const __bf16* Qp = Q + ((size_t)b * NH_ + h) * T_ * HD_;
  const __bf16* Kp = Kb + ((size_t)b * NKV_ + kvh) * T_ * HD_;
  const __bf16* Vp = Vt + ((size_t)b * NKV_ + kvh) * HD_ * T_;
  const int qw = qi * 64 + wave * 16;               // this wave's first q-row
  const int srow = tid >> 3, kc = tid & 7;          // staging: 8x16B chunks/row

  // Q fragments (A-layout); Q already pre-scaled by 1/8*log2e in rope_qk
  bf16x8 qf[2];
  #pragma unroll
  for (int c = 0; c < 2; ++c)
    qf[c] = *(const bf16x8*)&Qp[(size_t)(qw + r16) * HD_ + (c * 4 + g) * 8];

  f32x4 o[4] = {};
  float m[4], l[4];
  #pragma unroll
  for (int j = 0; j < 4; ++j) { m[j] = -__builtin_inff(); l[j] = 0.0f; }

  const int ntiles = qi + 1;
  u32x4 ka[2], va[2];
  #pragma unroll
  for (int p = 0; p < 2; ++p) {
    const int row = p * 32 + srow;
    ka[p] = *(const u32x4*)&Kp[(size_t)row * HD_ + kc * 8];
    va[p] = *(const u32x4*)&Vp[(size_t)row * T_ + kc * 8];
  }

  for (int t = 0; t < ntiles; ++t) {
    const int kv0 = t << 6;
    __syncthreads();  // prior iteration's LDS reads complete before overwrite
    #pragma unroll
    for (int p = 0; p < 2; ++p) {
      const int row = p * 32 + srow;
      const int sw = (kc ^ (row & 7)) * 8;
      *(u32x4*)&lK[row * 64 + sw] = ka[p];
      *(u32x4*)&lV[row * 64 + sw] = va[p];
    }
    __syncthreads();
    if (t + 1 < ntiles) {  // prefetch next tile; latency hides under compute
      const int nk = kv0 + 64;
      #pragma unroll
      for (int p = 0; p < 2; ++p) {
        const int row = p * 32 + srow;
        ka[p] = *(const u32x4*)&Kp[(size_t)(nk + row) * HD_ + kc * 8];
        va[p] = *(const u32x4*)&Vp[(size_t)row * T_ + nk + kc * 8];
      }
    }

    // ---- QK^T (exp2 domain): S[q][kv], 8 MFMAs ----
    f32x4 s[4] = {};
    #pragma unroll
    for (int c = 0; c < 2; ++c) {
      bf16x8 kf[4];
      #pragma unroll
      for (int ni = 0; ni < 4; ++ni) {
        const int row = ni * 16 + r16;
        kf[ni] = *(const bf16x8*)&lK[row * 64 + ((c * 4 + g) ^ (row & 7)) * 8];
      }
      #pragma unroll
      for (int ni = 0; ni < 4; ++ni)
        s[ni] = __builtin_amdgcn_mfma_f32_16x16x32_bf16(qf[c], kf[ni], s[ni], 0, 0, 0);
    }

    // ---- causal mask (last tile only) ----
    if (t == ntiles - 1) {
      #pragma unroll
      for (int ni = 0; ni < 4; ++ni)
        #pragma unroll
        for (int j = 0; j < 4; ++j)
          if (kv0 + ni * 16 + r16 > qw + g * 4 + j) s[ni][j] = -__builtin_inff();
    }

    // ---- online softmax (exp2, deferred-max) + P write ----
    #pragma unroll
    for (int j = 0; j < 4; ++j) {
      float pm = fmaxf(fmaxf(s[0][j], s[1][j]), fmaxf(s[2][j], s[3][j]));
      #pragma unroll
      for (int off = 8; off; off >>= 1) pm = fmaxf(pm, __shfl_xor(pm, off, 16));
      if (pm > m[j] + 8.0f) {  // rescale only when max grew materially (T13)
        const float sc = exp2f(m[j] - pm);
        l[j] *= sc;
        #pragma unroll
        for (int nf = 0; nf < 4; ++nf) o[nf][j] *= sc;
        m[j] = pm;
      }
      float p_[4], rs = 0.0f;
      #pragma unroll
      for (int ni = 0; ni < 4; ++ni) { p_[ni] = exp2f(s[ni][j] - m[j]); rs += p_[ni]; }
      #pragma unroll
      for (int off = 8; off; off >>= 1) rs += __shfl_xor(rs, off, 16);
      l[j] += rs;
      const int rp = g * 4 + j;
      #pragma unroll
      for (int ni = 0; ni < 4; ++ni) {
        const int col = ni * 16 + r16;
        pP[wave][rp * 64 + (((col >> 3) ^ (rp & 7)) * 8) + (col & 7)] = (__bf16)p_[ni];
      }
    }
    asm volatile("s_waitcnt lgkmcnt(0)" ::: "memory");
    __builtin_amdgcn_sched_barrier(0);

    // ---- PV: O += P * V^T, 8 MFMAs ----
    #pragma unroll
    for (int c = 0; c < 2; ++c) {
      const bf16x8 pf = *(const bf16x8*)&pP[wave][r16 * 64 + (((c * 4 + g) ^ (r16 & 7)) * 8)];
      #pragma unroll
      for (int nf = 0; nf < 4; ++nf) {
        const int row = nf * 16 + r16;
        const bf16x8 vf = *(const bf16x8*)&lV[row * 64 + (((c * 4 + g)) ^ (row & 7)) * 8];
        o[nf] = __builtin_amdgcn_mfma_f32_16x16x32_bf16(pf, vf, o[nf], 0, 0, 0);
      }
    }
  }

  // ---- epilogue -> Y[b][t][h][d] bf16 ----
  #pragma unroll
  for (int j = 0; j < 4; ++j) {
    const float inv = 1.0f / l[j];
    const int t = qw + g * 4 + j;
    #pragma unroll
    for (int nf = 0; nf < 4; ++nf) {
      const int d = nf * 16 + r16;
      Y[(((size_t)b * T_ + t) * NH_ + h) * HD_ + d] = (__bf16)(o[nf][j] * inv);
    }
  }
}

extern "C" void kernel_launch(void* const* d_in, const int* in_sizes, int n_in,
                              void* d_out, int out_size, void* d_ws, size_t ws_size,
                              hipStream_t stream) {
  const float* x = (const float*)d_in[0];
  const float* Wqkv = (const float*)d_in[1];
  const float* Wproj = (const float*)d_in[2];
  float* out = (float*)d_out;

  char* ws = (char*)d_ws;
  size_t off = 0;
  auto alloc = [&](size_t bytes) {
    char* p = ws + off;
    off += (bytes + 255) & ~(size_t)255;
    return p;
  };
  __bf16* xb     = (__bf16*)alloc((size_t)M_ * C_ * 2);          // 8 MB
  __bf16* wqkvT  = (__bf16*)alloc((size_t)NQKV_ * C_ * 2);       // 3 MB
  __bf16* wprojT = (__bf16*)alloc((size_t)C_ * C_ * 2);          // 2 MB
  float*  cosT   = (float*)alloc((size_t)T_ * 32 * 4);
  float*  sinT   = (float*)alloc((size_t)T_ * 32 * 4);
  float*  qkv    = (float*)alloc((size_t)M_ * NQKV_ * 4);        // 25 MB
  __bf16* Qb     = (__bf16*)alloc((size_t)B_ * NH_ * T_ * HD_ * 2);
  __bf16* Kb     = (__bf16*)alloc((size_t)B_ * NKV_ * T_ * HD_ * 2);
  __bf16* Vt     = (__bf16*)alloc((size_t)B_ * NKV_ * T_ * HD_ * 2);
  __bf16* Yb     = (__bf16*)alloc((size_t)M_ * C_ * 2);          // 8 MB

  hipLaunchKernelGGL(cast_x_kernel, dim3(M_ * C_ / 4 / 256), dim3(256), 0, stream, x, xb);
  hipLaunchKernelGGL(transpose_cast_kernel, dim3(NQKV_ / 64, C_ / 64), dim3(256), 0, stream,
                     Wqkv, wqkvT, C_, NQKV_);
  hipLaunchKernelGGL(transpose_cast_kernel, dim3(C_ / 64, C_ / 64), dim3(256), 0, stream,
                     Wproj, wprojT, C_, C_);
  hipLaunchKernelGGL(rope_table_kernel, dim3(T_ * 32 / 256), dim3(256), 0, stream, cosT, sinT);
  hipLaunchKernelGGL(gemm_tn_kernel, dim3(NQKV_ / 128, M_ / 128), dim3(256), 0, stream,
                     xb, wqkvT, qkv, NQKV_, C_);
  hipLaunchKernelGGL(rope_qk_kernel, dim3(M_ * (NH_ + NKV_) * 32 / 256), dim3(256), 0, stream,
                     qkv, cosT, sinT, Qb, Kb);
  hipLaunchKernelGGL(v_transpose_kernel, dim3(B_ * NKV_ * (T_ / 64)), dim3(256), 0, stream,
                     qkv, Vt);
  hipLaunchKernelGGL(attn_kernel, dim3(T_ / 64, B_ * NH_), dim3(256), 0, stream, Qb, Kb, Vt, Yb);
  hipLaunchKernelGGL(gemm_tn_kernel, dim3(C_ / 128, M_ / 128), dim3(256), 0, stream,
                     Yb, wprojT, out, C_, C_);
}

// Round 4
// 153.019 us; speedup vs baseline: 1.4122x; 1.4122x over previous
//
#include <hip/hip_runtime.h>
#include <hip/hip_bf16.h>

#define B_ 2
#define T_ 2048
#define C_ 1024
#define NH_ 16
#define NKV_ 4
#define HD_ 64
#define NQKV_ 1536           // (NH + 2*NKV) * HD
#define M_ 4096              // B_ * T_

typedef __attribute__((ext_vector_type(8))) __bf16 bf16x8;
typedef __attribute__((ext_vector_type(4))) __bf16 bf16x4;
typedef __attribute__((ext_vector_type(4))) float f32x4;
typedef __attribute__((ext_vector_type(4))) unsigned int u32x4;

// ---------------- cast x (fp32 -> bf16), 4 elems/thread ----------------
__global__ __launch_bounds__(256) void cast_x_kernel(const float* __restrict__ in,
                                                     __bf16* __restrict__ out) {
  const int i = blockIdx.x * 256 + threadIdx.x;
  const float4 v = ((const float4*)in)[i];
  bf16x4 o;
  o.x = (__bf16)v.x; o.y = (__bf16)v.y; o.z = (__bf16)v.z; o.w = (__bf16)v.w;
  ((bf16x4*)out)[i] = o;
}

// ---------- transpose + cast: in [K][N] fp32 -> out [N][K] bf16 ----------
__global__ __launch_bounds__(256) void transpose_cast_kernel(const float* __restrict__ in,
                                                             __bf16* __restrict__ out,
                                                             int K, int N) {
  __shared__ __bf16 tile[64][72];  // [n_local][k_local], padded
  const int n0 = blockIdx.x * 64, k0 = blockIdx.y * 64;
  const int tid = threadIdx.x;
  const int tr = tid >> 4, tc4 = (tid & 15) << 2;
  #pragma unroll
  for (int p = 0; p < 4; ++p) {
    const int k = k0 + p * 16 + tr;
    const float4 v = *(const float4*)&in[(size_t)k * N + n0 + tc4];
    tile[tc4 + 0][p * 16 + tr] = (__bf16)v.x;
    tile[tc4 + 1][p * 16 + tr] = (__bf16)v.y;
    tile[tc4 + 2][p * 16 + tr] = (__bf16)v.z;
    tile[tc4 + 3][p * 16 + tr] = (__bf16)v.w;
  }
  __syncthreads();
  #pragma unroll
  for (int p = 0; p < 4; ++p) {
    const int n = n0 + p * 16 + tr;
    bf16x4 o;
    o.x = tile[p * 16 + tr][tc4 + 0];
    o.y = tile[p * 16 + tr][tc4 + 1];
    o.z = tile[p * 16 + tr][tc4 + 2];
    o.w = tile[p * 16 + tr][tc4 + 3];
    *(bf16x4*)&out[(size_t)n * K + k0 + tc4] = o;
  }
}

// ---------------- RoPE cos/sin tables [T][32] fp32 ----------------
__global__ __launch_bounds__(256) void rope_table_kernel(float* __restrict__ cosT,
                                                         float* __restrict__ sinT) {
  const int idx = blockIdx.x * 256 + threadIdx.x;  // T*32 total
  const int t = idx >> 5, i = idx & 31;
  const float inv = powf(10000.0f, -(float)i * (1.0f / 32.0f));
  const float ang = (float)t * inv;
  cosT[idx] = cosf(ang);
  sinT[idx] = sinf(ang);
}

// ------- bf16 TN GEMM: A[M][K] * Bt[N][K]^T -> C[M][N] fp32 -------
// 128x128 tile, BK=64, 4 waves (2x2), reg-staged LDS with XOR swizzle.
__global__ __launch_bounds__(256) void gemm_tn_kernel(const __bf16* __restrict__ A,
                                                      const __bf16* __restrict__ Bt,
                                                      float* __restrict__ C, int N, int K) {
  __shared__ __align__(16) __bf16 lA[128 * 64];
  __shared__ __align__(16) __bf16 lB[128 * 64];
  const int tid = threadIdx.x;
  const int lane = tid & 63;
  const int wave = tid >> 6;
  const int wr = wave >> 1, wc = wave & 1;
  const int m0 = blockIdx.y * 128, n0 = blockIdx.x * 128;
  const int srow = tid >> 3, kc = tid & 7;  // staging: 8 threads/row, 16B chunks
  const int r16 = lane & 15, g = lane >> 4;
  f32x4 acc[4][4] = {};
  for (int k0 = 0; k0 < K; k0 += 64) {
    u32x4 ra[4], rb[4];
    #pragma unroll
    for (int p = 0; p < 4; ++p) {
      const int row = p * 32 + srow;
      ra[p] = *(const u32x4*)&A[(size_t)(m0 + row) * K + k0 + kc * 8];
      rb[p] = *(const u32x4*)&Bt[(size_t)(n0 + row) * K + k0 + kc * 8];
    }
    __syncthreads();  // prior iter's ds_reads done before overwrite
    #pragma unroll
    for (int p = 0; p < 4; ++p) {
      const int row = p * 32 + srow;
      const int sw = kc ^ (row & 7);  // bank-conflict swizzle (G4)
      *(u32x4*)&lA[row * 64 + sw * 8] = ra[p];
      *(u32x4*)&lB[row * 64 + sw * 8] = rb[p];
    }
    __syncthreads();
    #pragma unroll
    for (int ks = 0; ks < 64; ks += 32) {
      bf16x8 af[4], bfr[4];
      const int kch = (ks >> 3) + g;
      #pragma unroll
      for (int mi = 0; mi < 4; ++mi) {
        const int row = wr * 64 + mi * 16 + r16;
        af[mi] = *(const bf16x8*)&lA[row * 64 + (kch ^ (row & 7)) * 8];
      }
      #pragma unroll
      for (int ni = 0; ni < 4; ++ni) {
        const int row = wc * 64 + ni * 16 + r16;
        bfr[ni] = *(const bf16x8*)&lB[row * 64 + (kch ^ (row & 7)) * 8];
      }
      #pragma unroll
      for (int mi = 0; mi < 4; ++mi)
        #pragma unroll
        for (int ni = 0; ni < 4; ++ni)
          acc[mi][ni] = __builtin_amdgcn_mfma_f32_16x16x32_bf16(af[mi], bfr[ni], acc[mi][ni], 0, 0, 0);
    }
  }
  // epilogue: D layout col=lane&15, row=(lane>>4)*4+j
  #pragma unroll
  for (int mi = 0; mi < 4; ++mi) {
    const int r0 = m0 + wr * 64 + mi * 16 + g * 4;
    #pragma unroll
    for (int ni = 0; ni < 4; ++ni) {
      const int c = n0 + wc * 64 + ni * 16 + r16;
      #pragma unroll
      for (int j = 0; j < 4; ++j)
        C[(size_t)(r0 + j) * N + c] = acc[mi][ni][j];
    }
  }
}

// ---- RoPE on q,k (from fp32 qkv) -> Q[b][h][t][d], K[b][kvh][t][d] bf16 ----
// Q is additionally pre-scaled by 1/8 * log2(e) (softmax runs in exp2 domain).
__global__ __launch_bounds__(256) void rope_qk_kernel(const float* __restrict__ qkv,
                                                      const float* __restrict__ cosT,
                                                      const float* __restrict__ sinT,
                                                      __bf16* __restrict__ Q,
                                                      __bf16* __restrict__ Kb) {
  const int idx = blockIdx.x * 256 + threadIdx.x;  // M_*(NH+NKV)*32 total
  const int i = idx & 31;
  const int rest = idx >> 5;
  const int head = rest % (NH_ + NKV_);
  const int row = rest / (NH_ + NKV_);
  const int b = row >> 11, t = row & 2047;
  const float c = cosT[t * 32 + i], s = sinT[t * 32 + i];
  if (head < NH_) {
    const float* p = &qkv[(size_t)row * NQKV_ + head * HD_ + 2 * i];
    const float o1 = p[0] * c - p[1] * s;
    const float o2 = p[0] * s + p[1] * c;
    __bf16* q = &Q[(((size_t)b * NH_ + head) * T_ + t) * HD_ + 2 * i];
    const float qs = 0.125f * 1.44269504f;
    q[0] = (__bf16)(o1 * qs); q[1] = (__bf16)(o2 * qs);
  } else {
    const int kh = head - NH_;
    const float* p = &qkv[(size_t)row * NQKV_ + NH_ * HD_ + kh * HD_ + 2 * i];
    const float o1 = p[0] * c - p[1] * s;
    const float o2 = p[0] * s + p[1] * c;
    __bf16* k = &Kb[(((size_t)b * NKV_ + kh) * T_ + t) * HD_ + 2 * i];
    k[0] = (__bf16)o1; k[1] = (__bf16)o2;
  }
}

// ---- V transpose: qkv v-part -> Vt[b][kvh][d][t] bf16 (LDS tiled) ----
__global__ __launch_bounds__(256) void v_transpose_kernel(const float* __restrict__ qkv,
                                                          __bf16* __restrict__ Vt) {
  __shared__ __bf16 tile[64][72];  // [d][t_local], padded
  const int blk = blockIdx.x;      // B*NKV*(T/64)
  const int t0 = (blk & 31) * 64;
  const int kvh = (blk >> 5) & 3;
  const int b = blk >> 7;
  const int tid = threadIdx.x;
  const int tr = tid >> 4, c4 = (tid & 15) << 2;
  #pragma unroll
  for (int p = 0; p < 4; ++p) {
    const int t = t0 + p * 16 + tr;
    const float4 v = *(const float4*)&qkv[(size_t)(b * T_ + t) * NQKV_ + (NH_ + NKV_) * HD_ + kvh * HD_ + c4];
    tile[c4 + 0][p * 16 + tr] = (__bf16)v.x;
    tile[c4 + 1][p * 16 + tr] = (__bf16)v.y;
    tile[c4 + 2][p * 16 + tr] = (__bf16)v.z;
    tile[c4 + 3][p * 16 + tr] = (__bf16)v.w;
  }
  __syncthreads();
  #pragma unroll
  for (int p = 0; p < 4; ++p) {
    const int d = p * 16 + tr;
    bf16x4 o;
    o.x = tile[d][c4 + 0]; o.y = tile[d][c4 + 1];
    o.z = tile[d][c4 + 2]; o.w = tile[d][c4 + 3];
    *(bf16x4*)&Vt[(((size_t)b * NKV_ + kvh) * HD_ + d) * T_ + t0 + c4] = o;
  }
}

// ---- flash attention, triangle-paired for uniform block work ----
// Block pair index i handles q-tiles {i, 31-i} (64 rows each) in ONE shared KV
// sweep of 32-i tiles; side A (q-tile i) active for first i+1 tiles, side B
// always. Every block does exactly 33 tile-activations -> no causal tail.
// 4 waves x 16 rows per side; K/V staged in XOR-swizzled LDS; exp2-domain
// online softmax with deferred-max; reg prefetch of next K/V tile.
__global__ __launch_bounds__(256) void attn_kernel(const __bf16* __restrict__ Q,
                                                   const __bf16* __restrict__ Kb,
                                                   const __bf16* __restrict__ Vt,
                                                   __bf16* __restrict__ Y) {
  __shared__ __align__(16) __bf16 lK[64 * 64];      // [kv][d], swizzled
  __shared__ __align__(16) __bf16 lV[64 * 64];      // [d][kv], swizzled
  __shared__ __align__(16) __bf16 pP[4][16 * 64];   // per-wave [q][kv], swizzled
  const int tid = threadIdx.x;
  const int lane = tid & 63, wave = tid >> 6;
  const int r16 = lane & 15, g = lane >> 4;
  // bijective XCD swizzle (T1): 512 blocks, 8 XCDs -> 64 contiguous logical
  // ids per XCD so blocks sharing (b,kvh)'s K/V co-locate in one L2.
  const int logical = (blockIdx.x & 7) * 64 + (blockIdx.x >> 3);
  const int i = logical & 15;        // pair index: q-tiles {i, 31-i}
  const int bh = logical >> 4;
  const int b = bh >> 4, h = bh & 15;
  const int kvh = h >> 2;  // GQA rep = 4
  const __bf16* Qp = Q + ((size_t)b * NH_ + h) * T_ * HD_;
  const __bf16* Kp = Kb + ((size_t)b * NKV_ + kvh) * T_ * HD_;
  const __bf16* Vp = Vt + ((size_t)b * NKV_ + kvh) * HD_ * T_;
  const int qtile[2] = { i, 31 - i };
  const int srow = tid >> 3, kc = tid & 7;          // staging: 8x16B chunks/row

  // Q fragments (A-layout); Q pre-scaled by 1/8*log2e in rope_qk
  bf16x8 qf[2][2];
  #pragma unroll
  for (int sd = 0; sd < 2; ++sd)
    #pragma unroll
    for (int c = 0; c < 2; ++c)
      qf[sd][c] = *(const bf16x8*)&Qp[(size_t)(qtile[sd] * 64 + wave * 16 + r16) * HD_ + (c * 4 + g) * 8];

  f32x4 o[2][4] = {};
  float m[2][4], l[2][4];
  #pragma unroll
  for (int sd = 0; sd < 2; ++sd)
    #pragma unroll
    for (int j = 0; j < 4; ++j) { m[sd][j] = -__builtin_inff(); l[sd][j] = 0.0f; }

  const int ntiles = 32 - i;         // KV tiles needed by side B (q-tile 31-i)
  u32x4 ka[2], va[2];
  #pragma unroll
  for (int p = 0; p < 2; ++p) {
    const int row = p * 32 + srow;
    ka[p] = *(const u32x4*)&Kp[(size_t)row * HD_ + kc * 8];
    va[p] = *(const u32x4*)&Vp[(size_t)row * T_ + kc * 8];
  }

  for (int t = 0; t < ntiles; ++t) {
    const int kv0 = t << 6;
    __syncthreads();  // prior iteration's LDS reads complete before overwrite
    #pragma unroll
    for (int p = 0; p < 2; ++p) {
      const int row = p * 32 + srow;
      const int sw = (kc ^ (row & 7)) * 8;
      *(u32x4*)&lK[row * 64 + sw] = ka[p];
      *(u32x4*)&lV[row * 64 + sw] = va[p];
    }
    __syncthreads();
    if (t + 1 < ntiles) {  // prefetch next tile; latency hides under compute
      const int nk = kv0 + 64;
      #pragma unroll
      for (int p = 0; p < 2; ++p) {
        const int row = p * 32 + srow;
        ka[p] = *(const u32x4*)&Kp[(size_t)(nk + row) * HD_ + kc * 8];
        va[p] = *(const u32x4*)&Vp[(size_t)row * T_ + nk + kc * 8];
      }
    }

    #pragma unroll
    for (int sd = 0; sd < 2; ++sd) {
      if (sd == 0 && t > i) continue;       // side A inactive past its diagonal
      const int qw = qtile[sd] * 64 + wave * 16;

      // ---- QK^T (exp2 domain): 8 MFMAs ----
      f32x4 s[4] = {};
      #pragma unroll
      for (int c = 0; c < 2; ++c) {
        bf16x8 kf[4];
        #pragma unroll
        for (int ni = 0; ni < 4; ++ni) {
          const int row = ni * 16 + r16;
          kf[ni] = *(const bf16x8*)&lK[row * 64 + ((c * 4 + g) ^ (row & 7)) * 8];
        }
        #pragma unroll
        for (int ni = 0; ni < 4; ++ni)
          s[ni] = __builtin_amdgcn_mfma_f32_16x16x32_bf16(qf[sd][c], kf[ni], s[ni], 0, 0, 0);
      }

      // ---- causal mask (diagonal tile of this side only) ----
      if (t == qtile[sd]) {
        #pragma unroll
        for (int ni = 0; ni < 4; ++ni)
          #pragma unroll
          for (int j = 0; j < 4; ++j)
            if (kv0 + ni * 16 + r16 > qw + g * 4 + j) s[ni][j] = -__builtin_inff();
      }

      // ---- online softmax (exp2, deferred-max) + P write ----
      #pragma unroll
      for (int j = 0; j < 4; ++j) {
        float pm = fmaxf(fmaxf(s[0][j], s[1][j]), fmaxf(s[2][j], s[3][j]));
        #pragma unroll
        for (int off = 8; off; off >>= 1) pm = fmaxf(pm, __shfl_xor(pm, off, 16));
        if (pm > m[sd][j] + 8.0f) {  // rescale only when max grew materially
          const float sc = exp2f(m[sd][j] - pm);
          l[sd][j] *= sc;
          #pragma unroll
          for (int nf = 0; nf < 4; ++nf) o[sd][nf][j] *= sc;
          m[sd][j] = pm;
        }
        float p_[4], rs = 0.0f;
        #pragma unroll
        for (int ni = 0; ni < 4; ++ni) { p_[ni] = exp2f(s[ni][j] - m[sd][j]); rs += p_[ni]; }
        #pragma unroll
        for (int off = 8; off; off >>= 1) rs += __shfl_xor(rs, off, 16);
        l[sd][j] += rs;
        const int rp = g * 4 + j;
        #pragma unroll
        for (int ni = 0; ni < 4; ++ni) {
          const int col = ni * 16 + r16;
          pP[wave][rp * 64 + (((col >> 3) ^ (rp & 7)) * 8) + (col & 7)] = (__bf16)p_[ni];
        }
      }
      asm volatile("s_waitcnt lgkmcnt(0)" ::: "memory");
      __builtin_amdgcn_sched_barrier(0);

      // ---- PV: O += P * V^T, 8 MFMAs ----
      #pragma unroll
      for (int c = 0; c < 2; ++c) {
        const bf16x8 pf = *(const bf16x8*)&pP[wave][r16 * 64 + (((c * 4 + g) ^ (r16 & 7)) * 8)];
        #pragma unroll
        for (int nf = 0; nf < 4; ++nf) {
          const int row = nf * 16 + r16;
          const bf16x8 vf = *(const bf16x8*)&lV[row * 64 + ((c * 4 + g) ^ (row & 7)) * 8];
          o[sd][nf] = __builtin_amdgcn_mfma_f32_16x16x32_bf16(pf, vf, o[sd][nf], 0, 0, 0);
        }
      }
    }
  }

  // ---- epilogue -> Y[b][t][h][d] bf16 (both sides) ----
  #pragma unroll
  for (int sd = 0; sd < 2; ++sd) {
    const int qw = qtile[sd] * 64 + wave * 16;
    #pragma unroll
    for (int j = 0; j < 4; ++j) {
      const float inv = 1.0f / l[sd][j];
      const int t = qw + g * 4 + j;
      #pragma unroll
      for (int nf = 0; nf < 4; ++nf) {
        const int d = nf * 16 + r16;
        Y[(((size_t)b * T_ + t) * NH_ + h) * HD_ + d] = (__bf16)(o[sd][nf][j] * inv);
      }
    }
  }
}

extern "C" void kernel_launch(void* const* d_in, const int* in_sizes, int n_in,
                              void* d_out, int out_size, void* d_ws, size_t ws_size,
                              hipStream_t stream) {
  const float* x = (const float*)d_in[0];
  const float* Wqkv = (const float*)d_in[1];
  const float* Wproj = (const float*)d_in[2];
  float* out = (float*)d_out;

  char* ws = (char*)d_ws;
  size_t off = 0;
  auto alloc = [&](size_t bytes) {
    char* p = ws + off;
    off += (bytes + 255) & ~(size_t)255;
    return p;
  };
  __bf16* xb     = (__bf16*)alloc((size_t)M_ * C_ * 2);          // 8 MB
  __bf16* wqkvT  = (__bf16*)alloc((size_t)NQKV_ * C_ * 2);       // 3 MB
  __bf16* wprojT = (__bf16*)alloc((size_t)C_ * C_ * 2);          // 2 MB
  float*  cosT   = (float*)alloc((size_t)T_ * 32 * 4);
  float*  sinT   = (float*)alloc((size_t)T_ * 32 * 4);
  float*  qkv    = (float*)alloc((size_t)M_ * NQKV_ * 4);        // 25 MB
  __bf16* Qb     = (__bf16*)alloc((size_t)B_ * NH_ * T_ * HD_ * 2);
  __bf16* Kb     = (__bf16*)alloc((size_t)B_ * NKV_ * T_ * HD_ * 2);
  __bf16* Vt     = (__bf16*)alloc((size_t)B_ * NKV_ * T_ * HD_ * 2);
  __bf16* Yb     = (__bf16*)alloc((size_t)M_ * C_ * 2);          // 8 MB

  hipLaunchKernelGGL(cast_x_kernel, dim3(M_ * C_ / 4 / 256), dim3(256), 0, stream, x, xb);
  hipLaunchKernelGGL(transpose_cast_kernel, dim3(NQKV_ / 64, C_ / 64), dim3(256), 0, stream,
                     Wqkv, wqkvT, C_, NQKV_);
  hipLaunchKernelGGL(transpose_cast_kernel, dim3(C_ / 64, C_ / 64), dim3(256), 0, stream,
                     Wproj, wprojT, C_, C_);
  hipLaunchKernelGGL(rope_table_kernel, dim3(T_ * 32 / 256), dim3(256), 0, stream, cosT, sinT);
  hipLaunchKernelGGL(gemm_tn_kernel, dim3(NQKV_ / 128, M_ / 128), dim3(256), 0, stream,
                     xb, wqkvT, qkv, NQKV_, C_);
  hipLaunchKernelGGL(rope_qk_kernel, dim3(M_ * (NH_ + NKV_) * 32 / 256), dim3(256), 0, stream,
                     qkv, cosT, sinT, Qb, Kb);
  hipLaunchKernelGGL(v_transpose_kernel, dim3(B_ * NKV_ * (T_ / 64)), dim3(256), 0, stream,
                     qkv, Vt);
  hipLaunchKernelGGL(attn_kernel, dim3(16 * B_ * NH_), dim3(256), 0, stream, Qb, Kb, Vt, Yb);
  hipLaunchKernelGGL(gemm_tn_kernel, dim3(C_ / 128, M_ / 128), dim3(256), 0, stream,
                     Yb, wprojT, out, C_, C_);
}

// Round 5
// 128.254 us; speedup vs baseline: 1.6849x; 1.1931x over previous
//
#include <hip/hip_runtime.h>
#include <hip/hip_bf16.h>

#define B_ 2
#define T_ 2048
#define C_ 1024
#define NH_ 16
#define NKV_ 4
#define HD_ 64
#define NQKV_ 1536           // (NH + 2*NKV) * HD
#define M_ 4096              // B_ * T_

typedef __attribute__((ext_vector_type(8))) __bf16 bf16x8;
typedef __attribute__((ext_vector_type(4))) __bf16 bf16x4;
typedef __attribute__((ext_vector_type(4))) float f32x4;
typedef __attribute__((ext_vector_type(4))) unsigned int u32x4;

#define GLOAD_LDS16(gptr, lptr)                                                        \
  __builtin_amdgcn_global_load_lds(                                                    \
      (const __attribute__((address_space(1))) unsigned int*)(gptr),                   \
      (__attribute__((address_space(3))) unsigned int*)(lptr), 16, 0, 0)

// ---------------- cast x (fp32 -> bf16), 4 elems/thread ----------------
__global__ __launch_bounds__(256) void cast_x_kernel(const float* __restrict__ in,
                                                     __bf16* __restrict__ out) {
  const int i = blockIdx.x * 256 + threadIdx.x;
  const float4 v = ((const float4*)in)[i];
  bf16x4 o;
  o.x = (__bf16)v.x; o.y = (__bf16)v.y; o.z = (__bf16)v.z; o.w = (__bf16)v.w;
  ((bf16x4*)out)[i] = o;
}

// ---------- transpose + cast: in [K][N] fp32 -> out [N][K] bf16 ----------
__global__ __launch_bounds__(256) void transpose_cast_kernel(const float* __restrict__ in,
                                                             __bf16* __restrict__ out,
                                                             int K, int N) {
  __shared__ __bf16 tile[64][72];  // [n_local][k_local], padded
  const int n0 = blockIdx.x * 64, k0 = blockIdx.y * 64;
  const int tid = threadIdx.x;
  const int tr = tid >> 4, tc4 = (tid & 15) << 2;
  #pragma unroll
  for (int p = 0; p < 4; ++p) {
    const int k = k0 + p * 16 + tr;
    const float4 v = *(const float4*)&in[(size_t)k * N + n0 + tc4];
    tile[tc4 + 0][p * 16 + tr] = (__bf16)v.x;
    tile[tc4 + 1][p * 16 + tr] = (__bf16)v.y;
    tile[tc4 + 2][p * 16 + tr] = (__bf16)v.z;
    tile[tc4 + 3][p * 16 + tr] = (__bf16)v.w;
  }
  __syncthreads();
  #pragma unroll
  for (int p = 0; p < 4; ++p) {
    const int n = n0 + p * 16 + tr;
    bf16x4 o;
    o.x = tile[p * 16 + tr][tc4 + 0];
    o.y = tile[p * 16 + tr][tc4 + 1];
    o.z = tile[p * 16 + tr][tc4 + 2];
    o.w = tile[p * 16 + tr][tc4 + 3];
    *(bf16x4*)&out[(size_t)n * K + k0 + tc4] = o;
  }
}

// ---------------- RoPE cos/sin tables [T][32] fp32 ----------------
__global__ __launch_bounds__(256) void rope_table_kernel(float* __restrict__ cosT,
                                                         float* __restrict__ sinT) {
  const int idx = blockIdx.x * 256 + threadIdx.x;  // T*32 total
  const int t = idx >> 5, i = idx & 31;
  const float inv = powf(10000.0f, -(float)i * (1.0f / 32.0f));
  const float ang = (float)t * inv;
  cosT[idx] = cosf(ang);
  sinT[idx] = sinf(ang);
}

// ------- bf16 TN GEMM: A[M][K] * Bt[N][K]^T -> C[M][N] fp32 -------
// 128x128 tile, BK=64, 4 waves (2x2). global_load_lds (w=16) staging with
// pre-swizzled SOURCE + linear LDS dest (rule 21); reads swizzle identically.
__global__ __launch_bounds__(256) void gemm_tn_kernel(const __bf16* __restrict__ A,
                                                      const __bf16* __restrict__ Bt,
                                                      float* __restrict__ C, int N, int K) {
  __shared__ __align__(16) __bf16 lA[128 * 64];
  __shared__ __align__(16) __bf16 lB[128 * 64];
  const int tid = threadIdx.x;
  const int lane = tid & 63;
  const int wave = tid >> 6;
  const int wr = wave >> 1, wc = wave & 1;
  const int m0 = blockIdx.y * 128, n0 = blockIdx.x * 128;
  const int srow = tid >> 3, kc = tid & 7;  // staging: 8 threads/row, 16B chunks
  const int r16 = lane & 15, g = lane >> 4;
  f32x4 acc[4][4] = {};
  for (int k0 = 0; k0 < K; k0 += 64) {
    __syncthreads();  // prior iter's ds_reads done before overwrite
    #pragma unroll
    for (int p = 0; p < 4; ++p) {
      const int row = p * 32 + srow;
      const int sw = (kc ^ (row & 7)) * 8;       // inverse-swizzle the SOURCE
      GLOAD_LDS16(&A[(size_t)(m0 + row) * K + k0 + sw], &lA[row * 64 + kc * 8]);
      GLOAD_LDS16(&Bt[(size_t)(n0 + row) * K + k0 + sw], &lB[row * 64 + kc * 8]);
    }
    asm volatile("s_waitcnt vmcnt(0)" ::: "memory");
    __syncthreads();
    #pragma unroll
    for (int ks = 0; ks < 64; ks += 32) {
      bf16x8 af[4], bfr[4];
      const int kch = (ks >> 3) + g;
      #pragma unroll
      for (int mi = 0; mi < 4; ++mi) {
        const int row = wr * 64 + mi * 16 + r16;
        af[mi] = *(const bf16x8*)&lA[row * 64 + (kch ^ (row & 7)) * 8];
      }
      #pragma unroll
      for (int ni = 0; ni < 4; ++ni) {
        const int row = wc * 64 + ni * 16 + r16;
        bfr[ni] = *(const bf16x8*)&lB[row * 64 + (kch ^ (row & 7)) * 8];
      }
      __builtin_amdgcn_s_setprio(1);
      #pragma unroll
      for (int mi = 0; mi < 4; ++mi)
        #pragma unroll
        for (int ni = 0; ni < 4; ++ni)
          acc[mi][ni] = __builtin_amdgcn_mfma_f32_16x16x32_bf16(af[mi], bfr[ni], acc[mi][ni], 0, 0, 0);
      __builtin_amdgcn_s_setprio(0);
    }
  }
  // epilogue: D layout col=lane&15, row=(lane>>4)*4+j
  #pragma unroll
  for (int mi = 0; mi < 4; ++mi) {
    const int r0 = m0 + wr * 64 + mi * 16 + g * 4;
    #pragma unroll
    for (int ni = 0; ni < 4; ++ni) {
      const int c = n0 + wc * 64 + ni * 16 + r16;
      #pragma unroll
      for (int j = 0; j < 4; ++j)
        C[(size_t)(r0 + j) * N + c] = acc[mi][ni][j];
    }
  }
}

// ---- RoPE on q,k (from fp32 qkv) -> Q[b][h][t][d], K[b][kvh][t][d] bf16 ----
// Q is additionally pre-scaled by 1/8 * log2(e) (softmax runs in exp2 domain).
__global__ __launch_bounds__(256) void rope_qk_kernel(const float* __restrict__ qkv,
                                                      const float* __restrict__ cosT,
                                                      const float* __restrict__ sinT,
                                                      __bf16* __restrict__ Q,
                                                      __bf16* __restrict__ Kb) {
  const int idx = blockIdx.x * 256 + threadIdx.x;  // M_*(NH+NKV)*32 total
  const int i = idx & 31;
  const int rest = idx >> 5;
  const int head = rest % (NH_ + NKV_);
  const int row = rest / (NH_ + NKV_);
  const int b = row >> 11, t = row & 2047;
  const float c = cosT[t * 32 + i], s = sinT[t * 32 + i];
  if (head < NH_) {
    const float* p = &qkv[(size_t)row * NQKV_ + head * HD_ + 2 * i];
    const float o1 = p[0] * c - p[1] * s;
    const float o2 = p[0] * s + p[1] * c;
    __bf16* q = &Q[(((size_t)b * NH_ + head) * T_ + t) * HD_ + 2 * i];
    const float qs = 0.125f * 1.44269504f;
    q[0] = (__bf16)(o1 * qs); q[1] = (__bf16)(o2 * qs);
  } else {
    const int kh = head - NH_;
    const float* p = &qkv[(size_t)row * NQKV_ + NH_ * HD_ + kh * HD_ + 2 * i];
    const float o1 = p[0] * c - p[1] * s;
    const float o2 = p[0] * s + p[1] * c;
    __bf16* k = &Kb[(((size_t)b * NKV_ + kh) * T_ + t) * HD_ + 2 * i];
    k[0] = (__bf16)o1; k[1] = (__bf16)o2;
  }
}

// ---- V transpose: qkv v-part -> Vt[b][kvh][d][t] bf16 (LDS tiled) ----
__global__ __launch_bounds__(256) void v_transpose_kernel(const float* __restrict__ qkv,
                                                          __bf16* __restrict__ Vt) {
  __shared__ __bf16 tile[64][72];  // [d][t_local], padded
  const int blk = blockIdx.x;      // B*NKV*(T/64)
  const int t0 = (blk & 31) * 64;
  const int kvh = (blk >> 5) & 3;
  const int b = blk >> 7;
  const int tid = threadIdx.x;
  const int tr = tid >> 4, c4 = (tid & 15) << 2;
  #pragma unroll
  for (int p = 0; p < 4; ++p) {
    const int t = t0 + p * 16 + tr;
    const float4 v = *(const float4*)&qkv[(size_t)(b * T_ + t) * NQKV_ + (NH_ + NKV_) * HD_ + kvh * HD_ + c4];
    tile[c4 + 0][p * 16 + tr] = (__bf16)v.x;
    tile[c4 + 1][p * 16 + tr] = (__bf16)v.y;
    tile[c4 + 2][p * 16 + tr] = (__bf16)v.z;
    tile[c4 + 3][p * 16 + tr] = (__bf16)v.w;
  }
  __syncthreads();
  #pragma unroll
  for (int p = 0; p < 4; ++p) {
    const int d = p * 16 + tr;
    bf16x4 o;
    o.x = tile[d][c4 + 0]; o.y = tile[d][c4 + 1];
    o.z = tile[d][c4 + 2]; o.w = tile[d][c4 + 3];
    *(bf16x4*)&Vt[(((size_t)b * NKV_ + kvh) * HD_ + d) * T_ + t0 + c4] = o;
  }
}

// ---- flash attention, triangle-paired, SWAPPED-QK softmax ----
// Block pair index i handles q-tiles {i, 31-i} in one shared KV sweep (33
// tile-activations per block -> uniform). QK^T computed transposed
// (mfma(K,Q) -> S^T) so each lane owns the full row stats of q=qw+r16:
// row max/sum = in-lane tree + 2 shfl_xor (vs 32 shfls before). P packed
// as 4x8B swizzled ds_writes; PV unchanged. Deferred-max branchless.
__global__ __launch_bounds__(256) void attn_kernel(const __bf16* __restrict__ Q,
                                                   const __bf16* __restrict__ Kb,
                                                   const __bf16* __restrict__ Vt,
                                                   __bf16* __restrict__ Y) {
  __shared__ __align__(16) __bf16 lK[64 * 64];      // [kv][d], swizzled
  __shared__ __align__(16) __bf16 lV[64 * 64];      // [d][kv], swizzled
  __shared__ __align__(16) __bf16 pP[4][16 * 64];   // per-wave [q][kv], swizzled
  const int tid = threadIdx.x;
  const int lane = tid & 63, wave = tid >> 6;
  const int r16 = lane & 15, g = lane >> 4;
  // bijective XCD swizzle (T1): 512 blocks, 8 XCDs -> 64 contiguous logical
  // ids per XCD so blocks sharing (b,kvh)'s K/V co-locate in one L2.
  const int logical = (blockIdx.x & 7) * 64 + (blockIdx.x >> 3);
  const int i = logical & 15;        // pair index: q-tiles {i, 31-i}
  const int bh = logical >> 4;
  const int b = bh >> 4, h = bh & 15;
  const int kvh = h >> 2;  // GQA rep = 4
  const __bf16* Qp = Q + ((size_t)b * NH_ + h) * T_ * HD_;
  const __bf16* Kp = Kb + ((size_t)b * NKV_ + kvh) * T_ * HD_;
  const __bf16* Vp = Vt + ((size_t)b * NKV_ + kvh) * HD_ * T_;
  const int qtile[2] = { i, 31 - i };
  const int srow = tid >> 3, kc = tid & 7;          // staging: 8x16B chunks/row

  // Q fragments; Q pre-scaled by 1/8*log2e in rope_qk. Used as the B-operand
  // of the swapped QK^T mfma (cols = q = qw + r16).
  bf16x8 qf[2][2];
  #pragma unroll
  for (int sd = 0; sd < 2; ++sd)
    #pragma unroll
    for (int c = 0; c < 2; ++c)
      qf[sd][c] = *(const bf16x8*)&Qp[(size_t)(qtile[sd] * 64 + wave * 16 + r16) * HD_ + (c * 4 + g) * 8];

  f32x4 o[2][4] = {};
  float mS[2], lS[2];
  #pragma unroll
  for (int sd = 0; sd < 2; ++sd) { mS[sd] = -__builtin_inff(); lS[sd] = 0.0f; }

  const int ntiles = 32 - i;         // KV tiles needed by side B (q-tile 31-i)
  u32x4 ka[2], va[2];
  #pragma unroll
  for (int p = 0; p < 2; ++p) {
    const int row = p * 32 + srow;
    ka[p] = *(const u32x4*)&Kp[(size_t)row * HD_ + kc * 8];
    va[p] = *(const u32x4*)&Vp[(size_t)row * T_ + kc * 8];
  }

  for (int t = 0; t < ntiles; ++t) {
    const int kv0 = t << 6;
    __syncthreads();  // prior iteration's LDS reads complete before overwrite
    #pragma unroll
    for (int p = 0; p < 2; ++p) {
      const int row = p * 32 + srow;
      const int sw = (kc ^ (row & 7)) * 8;
      *(u32x4*)&lK[row * 64 + sw] = ka[p];
      *(u32x4*)&lV[row * 64 + sw] = va[p];
    }
    __syncthreads();
    if (t + 1 < ntiles) {  // prefetch next tile; latency hides under compute
      const int nk = kv0 + 64;
      #pragma unroll
      for (int p = 0; p < 2; ++p) {
        const int row = p * 32 + srow;
        ka[p] = *(const u32x4*)&Kp[(size_t)(nk + row) * HD_ + kc * 8];
        va[p] = *(const u32x4*)&Vp[(size_t)row * T_ + nk + kc * 8];
      }
    }

    #pragma unroll
    for (int sd = 0; sd < 2; ++sd) {
      if (sd == 0 && t > i) continue;       // side A inactive past its diagonal
      const int qw = qtile[sd] * 64 + wave * 16;

      // ---- QK^T swapped: s[ni][j] = S[kv0+ni*16+g*4+j][qw+r16] ----
      f32x4 s[4] = {};
      #pragma unroll
      for (int c = 0; c < 2; ++c) {
        bf16x8 kf[4];
        #pragma unroll
        for (int ni = 0; ni < 4; ++ni) {
          const int row = ni * 16 + r16;
          kf[ni] = *(const bf16x8*)&lK[row * 64 + ((c * 4 + g) ^ (row & 7)) * 8];
        }
        __builtin_amdgcn_s_setprio(1);
        #pragma unroll
        for (int ni = 0; ni < 4; ++ni)
          s[ni] = __builtin_amdgcn_mfma_f32_16x16x32_bf16(kf[ni], qf[sd][c], s[ni], 0, 0, 0);
        __builtin_amdgcn_s_setprio(0);
      }

      // ---- causal mask (diagonal tile of this side only) ----
      if (t == qtile[sd]) {
        #pragma unroll
        for (int ni = 0; ni < 4; ++ni)
          #pragma unroll
          for (int j = 0; j < 4; ++j)
            if (kv0 + ni * 16 + g * 4 + j > qw + r16) s[ni][j] = -__builtin_inff();
      }

      // ---- row max: in-lane tree + 2 shfl ----
      float pm;
      {
        f32x4 t4;
        #pragma unroll
        for (int j = 0; j < 4; ++j)
          t4[j] = fmaxf(fmaxf(s[0][j], s[1][j]), fmaxf(s[2][j], s[3][j]));
        pm = fmaxf(fmaxf(t4[0], t4[1]), fmaxf(t4[2], t4[3]));
        pm = fmaxf(pm, __shfl_xor(pm, 16));
        pm = fmaxf(pm, __shfl_xor(pm, 32));
      }
      // ---- deferred-max, branchless per-lane (sc==1.0 exactly when !upd) ----
      const bool upd = pm > mS[sd] + 8.0f;
      const float nm = upd ? pm : mS[sd];
      const float sc = exp2f(mS[sd] - nm);
      mS[sd] = nm;
      lS[sd] *= sc;
      if (__any(upd)) {  // redistribute sc from q=r16 layout to (g,j) layout
        #pragma unroll
        for (int j = 0; j < 4; ++j) {
          const float scj = __shfl(sc, g * 4 + j);
          #pragma unroll
          for (int nf = 0; nf < 4; ++nf) o[sd][nf][j] *= scj;
        }
      }
      // ---- P = exp2(S-m): in-lane sum + 2 shfl; pack bf16 ----
      float rs = 0.0f;
      bf16x4 pb[4];
      #pragma unroll
      for (int ni = 0; ni < 4; ++ni)
        #pragma unroll
        for (int j = 0; j < 4; ++j) {
          const float pv = exp2f(s[ni][j] - mS[sd]);
          rs += pv;
          pb[ni][j] = (__bf16)pv;
        }
      rs += __shfl_xor(rs, 16);
      rs += __shfl_xor(rs, 32);
      lS[sd] += rs;
      // ---- P write: row q=r16, kv-chunk 2ni+(g>>1), half g&1, swizzled ----
      #pragma unroll
      for (int ni = 0; ni < 4; ++ni) {
        const int ch = 2 * ni + (g >> 1);
        *(bf16x4*)&pP[wave][r16 * 64 + ((ch ^ (r16 & 7)) * 8) + (g & 1) * 4] = pb[ni];
      }
      asm volatile("s_waitcnt lgkmcnt(0)" ::: "memory");
      __builtin_amdgcn_sched_barrier(0);

      // ---- PV: O += P * V^T, 8 MFMAs ----
      __builtin_amdgcn_s_setprio(1);
      #pragma unroll
      for (int c = 0; c < 2; ++c) {
        const bf16x8 pf = *(const bf16x8*)&pP[wave][r16 * 64 + (((c * 4 + g) ^ (r16 & 7)) * 8)];
        #pragma unroll
        for (int nf = 0; nf < 4; ++nf) {
          const int row = nf * 16 + r16;
          const bf16x8 vf = *(const bf16x8*)&lV[row * 64 + ((c * 4 + g) ^ (row & 7)) * 8];
          o[sd][nf] = __builtin_amdgcn_mfma_f32_16x16x32_bf16(pf, vf, o[sd][nf], 0, 0, 0);
        }
      }
      __builtin_amdgcn_s_setprio(0);
    }
  }

  // ---- epilogue -> Y[b][t][h][d] bf16 (both sides); l via shfl ----
  #pragma unroll
  for (int sd = 0; sd < 2; ++sd) {
    const int qw = qtile[sd] * 64 + wave * 16;
    #pragma unroll
    for (int j = 0; j < 4; ++j) {
      const float lq = __shfl(lS[sd], g * 4 + j);
      const float inv = 1.0f / lq;
      const int tq = qw + g * 4 + j;
      #pragma unroll
      for (int nf = 0; nf < 4; ++nf) {
        const int d = nf * 16 + r16;
        Y[(((size_t)b * T_ + tq) * NH_ + h) * HD_ + d] = (__bf16)(o[sd][nf][j] * inv);
      }
    }
  }
}

extern "C" void kernel_launch(void* const* d_in, const int* in_sizes, int n_in,
                              void* d_out, int out_size, void* d_ws, size_t ws_size,
                              hipStream_t stream) {
  const float* x = (const float*)d_in[0];
  const float* Wqkv = (const float*)d_in[1];
  const float* Wproj = (const float*)d_in[2];
  float* out = (float*)d_out;

  char* ws = (char*)d_ws;
  size_t off = 0;
  auto alloc = [&](size_t bytes) {
    char* p = ws + off;
    off += (bytes + 255) & ~(size_t)255;
    return p;
  };
  __bf16* xb     = (__bf16*)alloc((size_t)M_ * C_ * 2);          // 8 MB
  __bf16* wqkvT  = (__bf16*)alloc((size_t)NQKV_ * C_ * 2);       // 3 MB
  __bf16* wprojT = (__bf16*)alloc((size_t)C_ * C_ * 2);          // 2 MB
  float*  cosT   = (float*)alloc((size_t)T_ * 32 * 4);
  float*  sinT   = (float*)alloc((size_t)T_ * 32 * 4);
  float*  qkv    = (float*)alloc((size_t)M_ * NQKV_ * 4);        // 25 MB
  __bf16* Qb     = (__bf16*)alloc((size_t)B_ * NH_ * T_ * HD_ * 2);
  __bf16* Kb     = (__bf16*)alloc((size_t)B_ * NKV_ * T_ * HD_ * 2);
  __bf16* Vt     = (__bf16*)alloc((size_t)B_ * NKV_ * T_ * HD_ * 2);
  __bf16* Yb     = (__bf16*)alloc((size_t)M_ * C_ * 2);          // 8 MB

  hipLaunchKernelGGL(cast_x_kernel, dim3(M_ * C_ / 4 / 256), dim3(256), 0, stream, x, xb);
  hipLaunchKernelGGL(transpose_cast_kernel, dim3(NQKV_ / 64, C_ / 64), dim3(256), 0, stream,
                     Wqkv, wqkvT, C_, NQKV_);
  hipLaunchKernelGGL(transpose_cast_kernel, dim3(C_ / 64, C_ / 64), dim3(256), 0, stream,
                     Wproj, wprojT, C_, C_);
  hipLaunchKernelGGL(rope_table_kernel, dim3(T_ * 32 / 256), dim3(256), 0, stream, cosT, sinT);
  hipLaunchKernelGGL(gemm_tn_kernel, dim3(NQKV_ / 128, M_ / 128), dim3(256), 0, stream,
                     xb, wqkvT, qkv, NQKV_, C_);
  hipLaunchKernelGGL(rope_qk_kernel, dim3(M_ * (NH_ + NKV_) * 32 / 256), dim3(256), 0, stream,
                     qkv, cosT, sinT, Qb, Kb);
  hipLaunchKernelGGL(v_transpose_kernel, dim3(B_ * NKV_ * (T_ / 64)), dim3(256), 0, stream,
                     qkv, Vt);
  hipLaunchKernelGGL(attn_kernel, dim3(16 * B_ * NH_), dim3(256), 0, stream, Qb, Kb, Vt, Yb);
  hipLaunchKernelGGL(gemm_tn_kernel, dim3(C_ / 128, M_ / 128), dim3(256), 0, stream,
                     Yb, wprojT, out, C_, C_);
}

// Round 6
// 127.566 us; speedup vs baseline: 1.6940x; 1.0054x over previous
//
#include <hip/hip_runtime.h>
#include <hip/hip_bf16.h>

#define B_ 2
#define T_ 2048
#define C_ 1024
#define NH_ 16
#define NKV_ 4
#define HD_ 64
#define NQKV_ 1536           // (NH + 2*NKV) * HD
#define M_ 4096              // B_ * T_

typedef __attribute__((ext_vector_type(8))) __bf16 bf16x8;
typedef __attribute__((ext_vector_type(4))) __bf16 bf16x4;
typedef __attribute__((ext_vector_type(4))) float f32x4;
typedef __attribute__((ext_vector_type(4))) unsigned int u32x4;

#define GLOAD_LDS16(gptr, lptr)                                                        \
  __builtin_amdgcn_global_load_lds(                                                    \
      (const __attribute__((address_space(1))) unsigned int*)(gptr),                   \
      (__attribute__((address_space(3))) unsigned int*)(lptr), 16, 0, 0)

// ---------------- cast x (fp32 -> bf16), 4 elems/thread ----------------
__global__ __launch_bounds__(256) void cast_x_kernel(const float* __restrict__ in,
                                                     __bf16* __restrict__ out) {
  const int i = blockIdx.x * 256 + threadIdx.x;
  const float4 v = ((const float4*)in)[i];
  bf16x4 o;
  o.x = (__bf16)v.x; o.y = (__bf16)v.y; o.z = (__bf16)v.z; o.w = (__bf16)v.w;
  ((bf16x4*)out)[i] = o;
}

// ---------- transpose + cast: in [K][N] fp32 -> out [N][K] bf16 ----------
__global__ __launch_bounds__(256) void transpose_cast_kernel(const float* __restrict__ in,
                                                             __bf16* __restrict__ out,
                                                             int K, int N) {
  __shared__ __bf16 tile[64][72];  // [n_local][k_local], padded
  const int n0 = blockIdx.x * 64, k0 = blockIdx.y * 64;
  const int tid = threadIdx.x;
  const int tr = tid >> 4, tc4 = (tid & 15) << 2;
  #pragma unroll
  for (int p = 0; p < 4; ++p) {
    const int k = k0 + p * 16 + tr;
    const float4 v = *(const float4*)&in[(size_t)k * N + n0 + tc4];
    tile[tc4 + 0][p * 16 + tr] = (__bf16)v.x;
    tile[tc4 + 1][p * 16 + tr] = (__bf16)v.y;
    tile[tc4 + 2][p * 16 + tr] = (__bf16)v.z;
    tile[tc4 + 3][p * 16 + tr] = (__bf16)v.w;
  }
  __syncthreads();
  #pragma unroll
  for (int p = 0; p < 4; ++p) {
    const int n = n0 + p * 16 + tr;
    bf16x4 o;
    o.x = tile[p * 16 + tr][tc4 + 0];
    o.y = tile[p * 16 + tr][tc4 + 1];
    o.z = tile[p * 16 + tr][tc4 + 2];
    o.w = tile[p * 16 + tr][tc4 + 3];
    *(bf16x4*)&out[(size_t)n * K + k0 + tc4] = o;
  }
}

// ---------------- RoPE cos/sin tables [T][32] fp32 ----------------
__global__ __launch_bounds__(256) void rope_table_kernel(float* __restrict__ cosT,
                                                         float* __restrict__ sinT) {
  const int idx = blockIdx.x * 256 + threadIdx.x;  // T*32 total
  const int t = idx >> 5, i = idx & 31;
  const float inv = powf(10000.0f, -(float)i * (1.0f / 32.0f));
  const float ang = (float)t * inv;
  cosT[idx] = cosf(ang);
  sinT[idx] = sinf(ang);
}

// ------- bf16 TN GEMM: A[M][K] * Bt[N][K]^T -> C[M][N] fp32 -------
// 128x128 tile, BK=64, 4 waves (2x2). Double-buffered global_load_lds (w=16):
// stage(t+1) issues BEFORE compute(t); vmcnt(0)+barrier once per tile.
// Pre-swizzled SOURCE + linear LDS dest (rule 21); reads swizzle identically.
__global__ __launch_bounds__(256) void gemm_tn_kernel(const __bf16* __restrict__ A,
                                                      const __bf16* __restrict__ Bt,
                                                      float* __restrict__ C, int N, int K) {
  __shared__ __align__(16) __bf16 lA[2][128 * 64];
  __shared__ __align__(16) __bf16 lB[2][128 * 64];
  const int tid = threadIdx.x;
  const int lane = tid & 63;
  const int wave = tid >> 6;
  const int wr = wave >> 1, wc = wave & 1;
  const int m0 = blockIdx.y * 128, n0 = blockIdx.x * 128;
  const int srow = tid >> 3, kc = tid & 7;  // staging: 8 threads/row, 16B chunks
  const int r16 = lane & 15, g = lane >> 4;
  f32x4 acc[4][4] = {};
  const int nt = K >> 6;

#define GSTAGE(buf, k0)                                                                   \
  {                                                                                       \
    _Pragma("unroll")                                                                     \
    for (int p = 0; p < 4; ++p) {                                                         \
      const int row = p * 32 + srow;                                                      \
      const int sw = (kc ^ (row & 7)) * 8;                                                \
      GLOAD_LDS16(&A[(size_t)(m0 + row) * K + (k0) + sw], &lA[buf][row * 64 + kc * 8]);   \
      GLOAD_LDS16(&Bt[(size_t)(n0 + row) * K + (k0) + sw], &lB[buf][row * 64 + kc * 8]);  \
    }                                                                                     \
  }

  GSTAGE(0, 0);
  asm volatile("s_waitcnt vmcnt(0)" ::: "memory");
  __syncthreads();
  int cur = 0;
  for (int t = 0; t < nt; ++t) {
    if (t + 1 < nt) GSTAGE(cur ^ 1, (t + 1) << 6);   // loads fly under compute
    #pragma unroll
    for (int ks = 0; ks < 64; ks += 32) {
      bf16x8 af[4], bfr[4];
      const int kch = (ks >> 3) + g;
      #pragma unroll
      for (int mi = 0; mi < 4; ++mi) {
        const int row = wr * 64 + mi * 16 + r16;
        af[mi] = *(const bf16x8*)&lA[cur][row * 64 + (kch ^ (row & 7)) * 8];
      }
      #pragma unroll
      for (int ni = 0; ni < 4; ++ni) {
        const int row = wc * 64 + ni * 16 + r16;
        bfr[ni] = *(const bf16x8*)&lB[cur][row * 64 + (kch ^ (row & 7)) * 8];
      }
      __builtin_amdgcn_s_setprio(1);
      #pragma unroll
      for (int mi = 0; mi < 4; ++mi)
        #pragma unroll
        for (int ni = 0; ni < 4; ++ni)
          acc[mi][ni] = __builtin_amdgcn_mfma_f32_16x16x32_bf16(af[mi], bfr[ni], acc[mi][ni], 0, 0, 0);
      __builtin_amdgcn_s_setprio(0);
    }
    asm volatile("s_waitcnt vmcnt(0)" ::: "memory");  // next-tile loads landed
    __syncthreads();
    cur ^= 1;
  }
  // epilogue: D layout col=lane&15, row=(lane>>4)*4+j
  #pragma unroll
  for (int mi = 0; mi < 4; ++mi) {
    const int r0 = m0 + wr * 64 + mi * 16 + g * 4;
    #pragma unroll
    for (int ni = 0; ni < 4; ++ni) {
      const int c = n0 + wc * 64 + ni * 16 + r16;
      #pragma unroll
      for (int j = 0; j < 4; ++j)
        C[(size_t)(r0 + j) * N + c] = acc[mi][ni][j];
    }
  }
#undef GSTAGE
}

// ---- RoPE on q,k (from fp32 qkv) -> Q[b][h][t][d], K[b][kvh][t][d] bf16 ----
// Q is additionally pre-scaled by 1/8 * log2(e) (softmax runs in exp2 domain).
__global__ __launch_bounds__(256) void rope_qk_kernel(const float* __restrict__ qkv,
                                                      const float* __restrict__ cosT,
                                                      const float* __restrict__ sinT,
                                                      __bf16* __restrict__ Q,
                                                      __bf16* __restrict__ Kb) {
  const int idx = blockIdx.x * 256 + threadIdx.x;  // M_*(NH+NKV)*32 total
  const int i = idx & 31;
  const int rest = idx >> 5;
  const int head = rest % (NH_ + NKV_);
  const int row = rest / (NH_ + NKV_);
  const int b = row >> 11, t = row & 2047;
  const float c = cosT[t * 32 + i], s = sinT[t * 32 + i];
  if (head < NH_) {
    const float* p = &qkv[(size_t)row * NQKV_ + head * HD_ + 2 * i];
    const float o1 = p[0] * c - p[1] * s;
    const float o2 = p[0] * s + p[1] * c;
    __bf16* q = &Q[(((size_t)b * NH_ + head) * T_ + t) * HD_ + 2 * i];
    const float qs = 0.125f * 1.44269504f;
    q[0] = (__bf16)(o1 * qs); q[1] = (__bf16)(o2 * qs);
  } else {
    const int kh = head - NH_;
    const float* p = &qkv[(size_t)row * NQKV_ + NH_ * HD_ + kh * HD_ + 2 * i];
    const float o1 = p[0] * c - p[1] * s;
    const float o2 = p[0] * s + p[1] * c;
    __bf16* k = &Kb[(((size_t)b * NKV_ + kh) * T_ + t) * HD_ + 2 * i];
    k[0] = (__bf16)o1; k[1] = (__bf16)o2;
  }
}

// ---- V transpose: qkv v-part -> Vt[b][kvh][d][t] bf16 (LDS tiled) ----
__global__ __launch_bounds__(256) void v_transpose_kernel(const float* __restrict__ qkv,
                                                          __bf16* __restrict__ Vt) {
  __shared__ __bf16 tile[64][72];  // [d][t_local], padded
  const int blk = blockIdx.x;      // B*NKV*(T/64)
  const int t0 = (blk & 31) * 64;
  const int kvh = (blk >> 5) & 3;
  const int b = blk >> 7;
  const int tid = threadIdx.x;
  const int tr = tid >> 4, c4 = (tid & 15) << 2;
  #pragma unroll
  for (int p = 0; p < 4; ++p) {
    const int t = t0 + p * 16 + tr;
    const float4 v = *(const float4*)&qkv[(size_t)(b * T_ + t) * NQKV_ + (NH_ + NKV_) * HD_ + kvh * HD_ + c4];
    tile[c4 + 0][p * 16 + tr] = (__bf16)v.x;
    tile[c4 + 1][p * 16 + tr] = (__bf16)v.y;
    tile[c4 + 2][p * 16 + tr] = (__bf16)v.z;
    tile[c4 + 3][p * 16 + tr] = (__bf16)v.w;
  }
  __syncthreads();
  #pragma unroll
  for (int p = 0; p < 4; ++p) {
    const int d = p * 16 + tr;
    bf16x4 o;
    o.x = tile[d][c4 + 0]; o.y = tile[d][c4 + 1];
    o.z = tile[d][c4 + 2]; o.w = tile[d][c4 + 3];
    *(bf16x4*)&Vt[(((size_t)b * NKV_ + kvh) * HD_ + d) * T_ + t0 + c4] = o;
  }
}

// ---- flash attention, triangle-paired, swapped-QK softmax, MERGED sides ----
// Block pair index i handles q-tiles {i, 31-i} in one shared KV sweep. For
// t<=i both sides are active and processed MERGED: one kf read feeds both QK
// MFMA sets, both softmax chains run back-to-back (2x ILP), ONE lgkm fence,
// one vf read feeds both PVs. For t>i only side B runs.
__global__ __launch_bounds__(256) void attn_kernel(const __bf16* __restrict__ Q,
                                                   const __bf16* __restrict__ Kb,
                                                   const __bf16* __restrict__ Vt,
                                                   __bf16* __restrict__ Y) {
  __shared__ __align__(16) __bf16 lK[64 * 64];        // [kv][d], swizzled
  __shared__ __align__(16) __bf16 lV[64 * 64];        // [d][kv], swizzled
  __shared__ __align__(16) __bf16 pP[4][2][16 * 64];  // per-wave per-side [q][kv]
  const int tid = threadIdx.x;
  const int lane = tid & 63, wave = tid >> 6;
  const int r16 = lane & 15, g = lane >> 4;
  // bijective XCD swizzle (T1): 512 blocks, 8 XCDs -> 64 contiguous logical
  // ids per XCD so blocks sharing (b,kvh)'s K/V co-locate in one L2.
  const int logical = (blockIdx.x & 7) * 64 + (blockIdx.x >> 3);
  const int i = logical & 15;        // pair index: q-tiles {i, 31-i}
  const int bh = logical >> 4;
  const int b = bh >> 4, h = bh & 15;
  const int kvh = h >> 2;  // GQA rep = 4
  const __bf16* Qp = Q + ((size_t)b * NH_ + h) * T_ * HD_;
  const __bf16* Kp = Kb + ((size_t)b * NKV_ + kvh) * T_ * HD_;
  const __bf16* Vp = Vt + ((size_t)b * NKV_ + kvh) * HD_ * T_;
  const int qtile[2] = { i, 31 - i };
  const int srow = tid >> 3, kc = tid & 7;          // staging: 8x16B chunks/row

  // Q fragments; pre-scaled by 1/8*log2e in rope_qk. B-operand of swapped QK.
  bf16x8 qf[2][2];
  #pragma unroll
  for (int sd = 0; sd < 2; ++sd)
    #pragma unroll
    for (int c = 0; c < 2; ++c)
      qf[sd][c] = *(const bf16x8*)&Qp[(size_t)(qtile[sd] * 64 + wave * 16 + r16) * HD_ + (c * 4 + g) * 8];

  f32x4 o[2][4] = {};
  float mS[2], lS[2];
  #pragma unroll
  for (int sd = 0; sd < 2; ++sd) { mS[sd] = -__builtin_inff(); lS[sd] = 0.0f; }

  // softmax + P-write for one side (lane owns full row q=qw+r16 of S^T)
  auto sm_side = [&](f32x4 (&s)[4], int sd) {
    f32x4 t4;
    #pragma unroll
    for (int j = 0; j < 4; ++j)
      t4[j] = fmaxf(fmaxf(s[0][j], s[1][j]), fmaxf(s[2][j], s[3][j]));
    float pm = fmaxf(fmaxf(t4[0], t4[1]), fmaxf(t4[2], t4[3]));
    pm = fmaxf(pm, __shfl_xor(pm, 16));
    pm = fmaxf(pm, __shfl_xor(pm, 32));
    const bool upd = pm > mS[sd] + 8.0f;   // deferred-max (T13)
    const float nm = upd ? pm : mS[sd];
    const float sc = exp2f(mS[sd] - nm);   // ==1.0 exactly when !upd
    mS[sd] = nm;
    lS[sd] *= sc;
    if (__any(upd)) {  // redistribute sc from q=r16 layout to (g,j) layout
      #pragma unroll
      for (int j = 0; j < 4; ++j) {
        const float scj = __shfl(sc, g * 4 + j);
        #pragma unroll
        for (int nf = 0; nf < 4; ++nf) o[sd][nf][j] *= scj;
      }
    }
    float rs = 0.0f;
    bf16x4 pb[4];
    #pragma unroll
    for (int ni = 0; ni < 4; ++ni)
      #pragma unroll
      for (int j = 0; j < 4; ++j) {
        const float pv = exp2f(s[ni][j] - mS[sd]);
        rs += pv;
        pb[ni][j] = (__bf16)pv;
      }
    rs += __shfl_xor(rs, 16);
    rs += __shfl_xor(rs, 32);
    lS[sd] += rs;
    #pragma unroll
    for (int ni = 0; ni < 4; ++ni) {   // row q=r16, kv-chunk 2ni+(g>>1), half g&1
      const int ch = 2 * ni + (g >> 1);
      *(bf16x4*)&pP[wave][sd][r16 * 64 + ((ch ^ (r16 & 7)) * 8) + (g & 1) * 4] = pb[ni];
    }
  };

  const int ntiles = 32 - i;         // KV tiles needed by side B (q-tile 31-i)
  u32x4 ka[2], va[2];
  #pragma unroll
  for (int p = 0; p < 2; ++p) {
    const int row = p * 32 + srow;
    ka[p] = *(const u32x4*)&Kp[(size_t)row * HD_ + kc * 8];
    va[p] = *(const u32x4*)&Vp[(size_t)row * T_ + kc * 8];
  }

  for (int t = 0; t < ntiles; ++t) {
    const int kv0 = t << 6;
    __syncthreads();  // prior iteration's LDS reads complete before overwrite
    #pragma unroll
    for (int p = 0; p < 2; ++p) {
      const int row = p * 32 + srow;
      const int sw = (kc ^ (row & 7)) * 8;
      *(u32x4*)&lK[row * 64 + sw] = ka[p];
      *(u32x4*)&lV[row * 64 + sw] = va[p];
    }
    __syncthreads();
    if (t + 1 < ntiles) {  // prefetch next tile; latency hides under compute
      const int nk = kv0 + 64;
      #pragma unroll
      for (int p = 0; p < 2; ++p) {
        const int row = p * 32 + srow;
        ka[p] = *(const u32x4*)&Kp[(size_t)(nk + row) * HD_ + kc * 8];
        va[p] = *(const u32x4*)&Vp[(size_t)row * T_ + nk + kc * 8];
      }
    }

    if (t <= i) {
      // ======== MERGED: both sides active ========
      f32x4 s0[4] = {}, s1[4] = {};
      #pragma unroll
      for (int c = 0; c < 2; ++c) {
        bf16x8 kf[4];
        #pragma unroll
        for (int ni = 0; ni < 4; ++ni) {
          const int row = ni * 16 + r16;
          kf[ni] = *(const bf16x8*)&lK[row * 64 + ((c * 4 + g) ^ (row & 7)) * 8];
        }
        __builtin_amdgcn_s_setprio(1);
        #pragma unroll
        for (int ni = 0; ni < 4; ++ni) {
          s0[ni] = __builtin_amdgcn_mfma_f32_16x16x32_bf16(kf[ni], qf[0][c], s0[ni], 0, 0, 0);
          s1[ni] = __builtin_amdgcn_mfma_f32_16x16x32_bf16(kf[ni], qf[1][c], s1[ni], 0, 0, 0);
        }
        __builtin_amdgcn_s_setprio(0);
      }
      if (t == i) {  // side A diagonal (side B never diagonal while t<=i<16)
        const int qw = qtile[0] * 64 + wave * 16;
        #pragma unroll
        for (int ni = 0; ni < 4; ++ni)
          #pragma unroll
          for (int j = 0; j < 4; ++j)
            if (kv0 + ni * 16 + g * 4 + j > qw + r16) s0[ni][j] = -__builtin_inff();
      }
      sm_side(s0, 0);
      sm_side(s1, 1);
      asm volatile("s_waitcnt lgkmcnt(0)" ::: "memory");
      // PV both sides, shared vf
      __builtin_amdgcn_s_setprio(1);
      #pragma unroll
      for (int c = 0; c < 2; ++c) {
        const bf16x8 pf0 = *(const bf16x8*)&pP[wave][0][r16 * 64 + (((c * 4 + g) ^ (r16 & 7)) * 8)];
        const bf16x8 pf1 = *(const bf16x8*)&pP[wave][1][r16 * 64 + (((c * 4 + g) ^ (r16 & 7)) * 8)];
        #pragma unroll
        for (int nf = 0; nf < 4; ++nf) {
          const int row = nf * 16 + r16;
          const bf16x8 vf = *(const bf16x8*)&lV[row * 64 + ((c * 4 + g) ^ (row & 7)) * 8];
          o[0][nf] = __builtin_amdgcn_mfma_f32_16x16x32_bf16(pf0, vf, o[0][nf], 0, 0, 0);
          o[1][nf] = __builtin_amdgcn_mfma_f32_16x16x32_bf16(pf1, vf, o[1][nf], 0, 0, 0);
        }
      }
      __builtin_amdgcn_s_setprio(0);
    } else {
      // ======== single side B ========
      const int qw = qtile[1] * 64 + wave * 16;
      f32x4 s[4] = {};
      #pragma unroll
      for (int c = 0; c < 2; ++c) {
        bf16x8 kf[4];
        #pragma unroll
        for (int ni = 0; ni < 4; ++ni) {
          const int row = ni * 16 + r16;
          kf[ni] = *(const bf16x8*)&lK[row * 64 + ((c * 4 + g) ^ (row & 7)) * 8];
        }
        __builtin_amdgcn_s_setprio(1);
        #pragma unroll
        for (int ni = 0; ni < 4; ++ni)
          s[ni] = __builtin_amdgcn_mfma_f32_16x16x32_bf16(kf[ni], qf[1][c], s[ni], 0, 0, 0);
        __builtin_amdgcn_s_setprio(0);
      }
      if (t == ntiles - 1) {  // side B diagonal
        #pragma unroll
        for (int ni = 0; ni < 4; ++ni)
          #pragma unroll
          for (int j = 0; j < 4; ++j)
            if (kv0 + ni * 16 + g * 4 + j > qw + r16) s[ni][j] = -__builtin_inff();
      }
      sm_side(s, 1);
      asm volatile("s_waitcnt lgkmcnt(0)" ::: "memory");
      __builtin_amdgcn_s_setprio(1);
      #pragma unroll
      for (int c = 0; c < 2; ++c) {
        const bf16x8 pf = *(const bf16x8*)&pP[wave][1][r16 * 64 + (((c * 4 + g) ^ (r16 & 7)) * 8)];
        #pragma unroll
        for (int nf = 0; nf < 4; ++nf) {
          const int row = nf * 16 + r16;
          const bf16x8 vf = *(const bf16x8*)&lV[row * 64 + ((c * 4 + g) ^ (row & 7)) * 8];
          o[1][nf] = __builtin_amdgcn_mfma_f32_16x16x32_bf16(pf, vf, o[1][nf], 0, 0, 0);
        }
      }
      __builtin_amdgcn_s_setprio(0);
    }
  }

  // ---- epilogue -> Y[b][t][h][d] bf16 (both sides); l via shfl ----
  #pragma unroll
  for (int sd = 0; sd < 2; ++sd) {
    const int qw = qtile[sd] * 64 + wave * 16;
    #pragma unroll
    for (int j = 0; j < 4; ++j) {
      const float lq = __shfl(lS[sd], g * 4 + j);
      const float inv = 1.0f / lq;
      const int tq = qw + g * 4 + j;
      #pragma unroll
      for (int nf = 0; nf < 4; ++nf) {
        const int d = nf * 16 + r16;
        Y[(((size_t)b * T_ + tq) * NH_ + h) * HD_ + d] = (__bf16)(o[sd][nf][j] * inv);
      }
    }
  }
}

extern "C" void kernel_launch(void* const* d_in, const int* in_sizes, int n_in,
                              void* d_out, int out_size, void* d_ws, size_t ws_size,
                              hipStream_t stream) {
  const float* x = (const float*)d_in[0];
  const float* Wqkv = (const float*)d_in[1];
  const float* Wproj = (const float*)d_in[2];
  float* out = (float*)d_out;

  char* ws = (char*)d_ws;
  size_t off = 0;
  auto alloc = [&](size_t bytes) {
    char* p = ws + off;
    off += (bytes + 255) & ~(size_t)255;
    return p;
  };
  __bf16* xb     = (__bf16*)alloc((size_t)M_ * C_ * 2);          // 8 MB
  __bf16* wqkvT  = (__bf16*)alloc((size_t)NQKV_ * C_ * 2);       // 3 MB
  __bf16* wprojT = (__bf16*)alloc((size_t)C_ * C_ * 2);          // 2 MB
  float*  cosT   = (float*)alloc((size_t)T_ * 32 * 4);
  float*  sinT   = (float*)alloc((size_t)T_ * 32 * 4);
  float*  qkv    = (float*)alloc((size_t)M_ * NQKV_ * 4);        // 25 MB
  __bf16* Qb     = (__bf16*)alloc((size_t)B_ * NH_ * T_ * HD_ * 2);
  __bf16* Kb     = (__bf16*)alloc((size_t)B_ * NKV_ * T_ * HD_ * 2);
  __bf16* Vt     = (__bf16*)alloc((size_t)B_ * NKV_ * T_ * HD_ * 2);
  __bf16* Yb     = (__bf16*)alloc((size_t)M_ * C_ * 2);          // 8 MB

  hipLaunchKernelGGL(cast_x_kernel, dim3(M_ * C_ / 4 / 256), dim3(256), 0, stream, x, xb);
  hipLaunchKernelGGL(transpose_cast_kernel, dim3(NQKV_ / 64, C_ / 64), dim3(256), 0, stream,
                     Wqkv, wqkvT, C_, NQKV_);
  hipLaunchKernelGGL(transpose_cast_kernel, dim3(C_ / 64, C_ / 64), dim3(256), 0, stream,
                     Wproj, wprojT, C_, C_);
  hipLaunchKernelGGL(rope_table_kernel, dim3(T_ * 32 / 256), dim3(256), 0, stream, cosT, sinT);
  hipLaunchKernelGGL(gemm_tn_kernel, dim3(NQKV_ / 128, M_ / 128), dim3(256), 0, stream,
                     xb, wqkvT, qkv, NQKV_, C_);
  hipLaunchKernelGGL(rope_qk_kernel, dim3(M_ * (NH_ + NKV_) * 32 / 256), dim3(256), 0, stream,
                     qkv, cosT, sinT, Qb, Kb);
  hipLaunchKernelGGL(v_transpose_kernel, dim3(B_ * NKV_ * (T_ / 64)), dim3(256), 0, stream,
                     qkv, Vt);
  hipLaunchKernelGGL(attn_kernel, dim3(16 * B_ * NH_), dim3(256), 0, stream, Qb, Kb, Vt, Yb);
  hipLaunchKernelGGL(gemm_tn_kernel, dim3(C_ / 128, M_ / 128), dim3(256), 0, stream,
                     Yb, wprojT, out, C_, C_);
}

// Round 7
// 123.236 us; speedup vs baseline: 1.7535x; 1.0351x over previous
//
#include <hip/hip_runtime.h>
#include <hip/hip_bf16.h>

#define B_ 2
#define T_ 2048
#define C_ 1024
#define NH_ 16
#define NKV_ 4
#define HD_ 64
#define NQKV_ 1536           // (NH + 2*NKV) * HD
#define M_ 4096              // B_ * T_

typedef __attribute__((ext_vector_type(8))) __bf16 bf16x8;
typedef __attribute__((ext_vector_type(4))) __bf16 bf16x4;
typedef __attribute__((ext_vector_type(4))) float f32x4;
typedef __attribute__((ext_vector_type(4))) unsigned int u32x4;

#define GLOAD_LDS16(gptr, lptr)                                                        \
  __builtin_amdgcn_global_load_lds(                                                    \
      (const __attribute__((address_space(1))) unsigned int*)(gptr),                   \
      (__attribute__((address_space(3))) unsigned int*)(lptr), 16, 0, 0)

// ---------------- cast x (fp32 -> bf16), 4 elems/thread ----------------
__global__ __launch_bounds__(256) void cast_x_kernel(const float* __restrict__ in,
                                                     __bf16* __restrict__ out) {
  const int i = blockIdx.x * 256 + threadIdx.x;
  const float4 v = ((const float4*)in)[i];
  bf16x4 o;
  o.x = (__bf16)v.x; o.y = (__bf16)v.y; o.z = (__bf16)v.z; o.w = (__bf16)v.w;
  ((bf16x4*)out)[i] = o;
}

// ---------- transpose + cast: in [K][N] fp32 -> out [N][K] bf16 ----------
__global__ __launch_bounds__(256) void transpose_cast_kernel(const float* __restrict__ in,
                                                             __bf16* __restrict__ out,
                                                             int K, int N) {
  __shared__ __bf16 tile[64][72];  // [n_local][k_local], padded
  const int n0 = blockIdx.x * 64, k0 = blockIdx.y * 64;
  const int tid = threadIdx.x;
  const int tr = tid >> 4, tc4 = (tid & 15) << 2;
  #pragma unroll
  for (int p = 0; p < 4; ++p) {
    const int k = k0 + p * 16 + tr;
    const float4 v = *(const float4*)&in[(size_t)k * N + n0 + tc4];
    tile[tc4 + 0][p * 16 + tr] = (__bf16)v.x;
    tile[tc4 + 1][p * 16 + tr] = (__bf16)v.y;
    tile[tc4 + 2][p * 16 + tr] = (__bf16)v.z;
    tile[tc4 + 3][p * 16 + tr] = (__bf16)v.w;
  }
  __syncthreads();
  #pragma unroll
  for (int p = 0; p < 4; ++p) {
    const int n = n0 + p * 16 + tr;
    bf16x4 o;
    o.x = tile[p * 16 + tr][tc4 + 0];
    o.y = tile[p * 16 + tr][tc4 + 1];
    o.z = tile[p * 16 + tr][tc4 + 2];
    o.w = tile[p * 16 + tr][tc4 + 3];
    *(bf16x4*)&out[(size_t)n * K + k0 + tc4] = o;
  }
}

// ---------------- RoPE cos/sin tables [T][32] fp32 ----------------
__global__ __launch_bounds__(256) void rope_table_kernel(float* __restrict__ cosT,
                                                         float* __restrict__ sinT) {
  const int idx = blockIdx.x * 256 + threadIdx.x;  // T*32 total
  const int t = idx >> 5, i = idx & 31;
  const float inv = powf(10000.0f, -(float)i * (1.0f / 32.0f));
  const float ang = (float)t * inv;
  cosT[idx] = cosf(ang);
  sinT[idx] = sinf(ang);
}

// ------- bf16 TN GEMM: A[M][K] * Bt[N][K]^T -> C[M][N] fp32 -------
// 128x128 tile, BK=64, 4 waves (2x2). Double-buffered global_load_lds (w=16):
// stage(t+1) issues BEFORE compute(t); vmcnt(0)+barrier once per tile.
// Pre-swizzled SOURCE + linear LDS dest (rule 21); reads swizzle identically.
__global__ __launch_bounds__(256) void gemm_tn_kernel(const __bf16* __restrict__ A,
                                                      const __bf16* __restrict__ Bt,
                                                      float* __restrict__ C, int N, int K) {
  __shared__ __align__(16) __bf16 lA[2][128 * 64];
  __shared__ __align__(16) __bf16 lB[2][128 * 64];
  const int tid = threadIdx.x;
  const int lane = tid & 63;
  const int wave = tid >> 6;
  const int wr = wave >> 1, wc = wave & 1;
  const int m0 = blockIdx.y * 128, n0 = blockIdx.x * 128;
  const int srow = tid >> 3, kc = tid & 7;  // staging: 8 threads/row, 16B chunks
  const int r16 = lane & 15, g = lane >> 4;
  f32x4 acc[4][4] = {};
  const int nt = K >> 6;

#define GSTAGE(buf, k0)                                                                   \
  {                                                                                       \
    _Pragma("unroll")                                                                     \
    for (int p = 0; p < 4; ++p) {                                                         \
      const int row = p * 32 + srow;                                                      \
      const int sw = (kc ^ (row & 7)) * 8;                                                \
      GLOAD_LDS16(&A[(size_t)(m0 + row) * K + (k0) + sw], &lA[buf][row * 64 + kc * 8]);   \
      GLOAD_LDS16(&Bt[(size_t)(n0 + row) * K + (k0) + sw], &lB[buf][row * 64 + kc * 8]);  \
    }                                                                                     \
  }

  GSTAGE(0, 0);
  asm volatile("s_waitcnt vmcnt(0)" ::: "memory");
  __syncthreads();
  int cur = 0;
  for (int t = 0; t < nt; ++t) {
    if (t + 1 < nt) GSTAGE(cur ^ 1, (t + 1) << 6);   // loads fly under compute
    #pragma unroll
    for (int ks = 0; ks < 64; ks += 32) {
      bf16x8 af[4], bfr[4];
      const int kch = (ks >> 3) + g;
      #pragma unroll
      for (int mi = 0; mi < 4; ++mi) {
        const int row = wr * 64 + mi * 16 + r16;
        af[mi] = *(const bf16x8*)&lA[cur][row * 64 + (kch ^ (row & 7)) * 8];
      }
      #pragma unroll
      for (int ni = 0; ni < 4; ++ni) {
        const int row = wc * 64 + ni * 16 + r16;
        bfr[ni] = *(const bf16x8*)&lB[cur][row * 64 + (kch ^ (row & 7)) * 8];
      }
      __builtin_amdgcn_s_setprio(1);
      #pragma unroll
      for (int mi = 0; mi < 4; ++mi)
        #pragma unroll
        for (int ni = 0; ni < 4; ++ni)
          acc[mi][ni] = __builtin_amdgcn_mfma_f32_16x16x32_bf16(af[mi], bfr[ni], acc[mi][ni], 0, 0, 0);
      __builtin_amdgcn_s_setprio(0);
    }
    asm volatile("s_waitcnt vmcnt(0)" ::: "memory");  // next-tile loads landed
    __syncthreads();
    cur ^= 1;
  }
  // epilogue: D layout col=lane&15, row=(lane>>4)*4+j
  #pragma unroll
  for (int mi = 0; mi < 4; ++mi) {
    const int r0 = m0 + wr * 64 + mi * 16 + g * 4;
    #pragma unroll
    for (int ni = 0; ni < 4; ++ni) {
      const int c = n0 + wc * 64 + ni * 16 + r16;
      #pragma unroll
      for (int j = 0; j < 4; ++j)
        C[(size_t)(r0 + j) * N + c] = acc[mi][ni][j];
    }
  }
#undef GSTAGE
}

// ---- RoPE on q,k (from fp32 qkv) -> Q[b][h][t][d], K[b][kvh][t][d] bf16 ----
// Q is additionally pre-scaled by 1/8 * log2(e) (softmax runs in exp2 domain).
__global__ __launch_bounds__(256) void rope_qk_kernel(const float* __restrict__ qkv,
                                                      const float* __restrict__ cosT,
                                                      const float* __restrict__ sinT,
                                                      __bf16* __restrict__ Q,
                                                      __bf16* __restrict__ Kb) {
  const int idx = blockIdx.x * 256 + threadIdx.x;  // M_*(NH+NKV)*32 total
  const int i = idx & 31;
  const int rest = idx >> 5;
  const int head = rest % (NH_ + NKV_);
  const int row = rest / (NH_ + NKV_);
  const int b = row >> 11, t = row & 2047;
  const float c = cosT[t * 32 + i], s = sinT[t * 32 + i];
  if (head < NH_) {
    const float* p = &qkv[(size_t)row * NQKV_ + head * HD_ + 2 * i];
    const float o1 = p[0] * c - p[1] * s;
    const float o2 = p[0] * s + p[1] * c;
    __bf16* q = &Q[(((size_t)b * NH_ + head) * T_ + t) * HD_ + 2 * i];
    const float qs = 0.125f * 1.44269504f;
    q[0] = (__bf16)(o1 * qs); q[1] = (__bf16)(o2 * qs);
  } else {
    const int kh = head - NH_;
    const float* p = &qkv[(size_t)row * NQKV_ + NH_ * HD_ + kh * HD_ + 2 * i];
    const float o1 = p[0] * c - p[1] * s;
    const float o2 = p[0] * s + p[1] * c;
    __bf16* k = &Kb[(((size_t)b * NKV_ + kh) * T_ + t) * HD_ + 2 * i];
    k[0] = (__bf16)o1; k[1] = (__bf16)o2;
  }
}

// ---- V transpose: qkv v-part -> Vt[b][kvh][d][t] bf16 (LDS tiled) ----
__global__ __launch_bounds__(256) void v_transpose_kernel(const float* __restrict__ qkv,
                                                          __bf16* __restrict__ Vt) {
  __shared__ __bf16 tile[64][72];  // [d][t_local], padded
  const int blk = blockIdx.x;      // B*NKV*(T/64)
  const int t0 = (blk & 31) * 64;
  const int kvh = (blk >> 5) & 3;
  const int b = blk >> 7;
  const int tid = threadIdx.x;
  const int tr = tid >> 4, c4 = (tid & 15) << 2;
  #pragma unroll
  for (int p = 0; p < 4; ++p) {
    const int t = t0 + p * 16 + tr;
    const float4 v = *(const float4*)&qkv[(size_t)(b * T_ + t) * NQKV_ + (NH_ + NKV_) * HD_ + kvh * HD_ + c4];
    tile[c4 + 0][p * 16 + tr] = (__bf16)v.x;
    tile[c4 + 1][p * 16 + tr] = (__bf16)v.y;
    tile[c4 + 2][p * 16 + tr] = (__bf16)v.z;
    tile[c4 + 3][p * 16 + tr] = (__bf16)v.w;
  }
  __syncthreads();
  #pragma unroll
  for (int p = 0; p < 4; ++p) {
    const int d = p * 16 + tr;
    bf16x4 o;
    o.x = tile[d][c4 + 0]; o.y = tile[d][c4 + 1];
    o.z = tile[d][c4 + 2]; o.w = tile[d][c4 + 3];
    *(bf16x4*)&Vt[(((size_t)b * NKV_ + kvh) * HD_ + d) * T_ + t0 + c4] = o;
  }
}

// ---- flash attention, triangle-paired, swapped-QK softmax, K/V LDS dbuf ----
// Block pair index i handles q-tiles {i, 31-i} in one shared KV sweep (33
// tile-activations/block -> uniform). K/V double-buffered in LDS, staged by
// global_load_lds (pre-swizzled source + linear dest); ONE barrier per tile;
// next tile's loads fly under this tile's compute. Swapped QK^T (mfma(K,Q))
// puts full row stats in-lane: max/sum = in-lane tree + 2 shfl_xor.
__global__ __launch_bounds__(256) void attn_kernel(const __bf16* __restrict__ Q,
                                                   const __bf16* __restrict__ Kb,
                                                   const __bf16* __restrict__ Vt,
                                                   __bf16* __restrict__ Y) {
  __shared__ __align__(16) __bf16 lK[2][64 * 64];   // [kv][d], swizzled
  __shared__ __align__(16) __bf16 lV[2][64 * 64];   // [d][kv], swizzled
  __shared__ __align__(16) __bf16 pP[4][16 * 64];   // per-wave [q][kv], swizzled
  const int tid = threadIdx.x;
  const int lane = tid & 63, wave = tid >> 6;
  const int r16 = lane & 15, g = lane >> 4;
  // bijective XCD swizzle (T1): 512 blocks, 8 XCDs -> 64 contiguous logical
  // ids per XCD so blocks sharing (b,kvh)'s K/V co-locate in one L2.
  const int logical = (blockIdx.x & 7) * 64 + (blockIdx.x >> 3);
  const int i = logical & 15;        // pair index: q-tiles {i, 31-i}
  const int bh = logical >> 4;
  const int b = bh >> 4, h = bh & 15;
  const int kvh = h >> 2;  // GQA rep = 4
  const __bf16* Qp = Q + ((size_t)b * NH_ + h) * T_ * HD_;
  const __bf16* Kp = Kb + ((size_t)b * NKV_ + kvh) * T_ * HD_;
  const __bf16* Vp = Vt + ((size_t)b * NKV_ + kvh) * HD_ * T_;
  const int qtile[2] = { i, 31 - i };
  const int srow = tid >> 3, kc = tid & 7;          // staging: 8x16B chunks/row

#define ASTAGE(buf, kv0_)                                                                  \
  {                                                                                        \
    _Pragma("unroll")                                                                      \
    for (int p = 0; p < 2; ++p) {                                                          \
      const int row = p * 32 + srow;                                                       \
      const int sw = (kc ^ (row & 7)) * 8;                                                 \
      GLOAD_LDS16(&Kp[(size_t)((kv0_) + row) * HD_ + sw], &lK[buf][row * 64 + kc * 8]);    \
      GLOAD_LDS16(&Vp[(size_t)row * T_ + (kv0_) + sw], &lV[buf][row * 64 + kc * 8]);       \
    }                                                                                      \
  }

  // Q fragments; pre-scaled by 1/8*log2e in rope_qk. B-operand of swapped QK.
  bf16x8 qf[2][2];
  #pragma unroll
  for (int sd = 0; sd < 2; ++sd)
    #pragma unroll
    for (int c = 0; c < 2; ++c)
      qf[sd][c] = *(const bf16x8*)&Qp[(size_t)(qtile[sd] * 64 + wave * 16 + r16) * HD_ + (c * 4 + g) * 8];

  f32x4 o[2][4] = {};
  float mS[2], lS[2];
  #pragma unroll
  for (int sd = 0; sd < 2; ++sd) { mS[sd] = -__builtin_inff(); lS[sd] = 0.0f; }

  // softmax + P-write for one side (lane owns full row q=qw+r16 of S^T)
  auto sm_side = [&](f32x4 (&s)[4], int sd) {
    // in-lane 16->1 max, max3-shaped triples (T17)
    float t0 = fmaxf(fmaxf(s[0][0], s[0][1]), s[0][2]);
    float t1 = fmaxf(fmaxf(s[0][3], s[1][0]), s[1][1]);
    float t2 = fmaxf(fmaxf(s[1][2], s[1][3]), s[2][0]);
    float t3 = fmaxf(fmaxf(s[2][1], s[2][2]), s[2][3]);
    float t4 = fmaxf(fmaxf(s[3][0], s[3][1]), s[3][2]);
    float pm = fmaxf(fmaxf(t0, t1), t2);
    pm = fmaxf(pm, fmaxf(t3, t4));
    pm = fmaxf(pm, s[3][3]);
    pm = fmaxf(pm, __shfl_xor(pm, 16));
    pm = fmaxf(pm, __shfl_xor(pm, 32));
    const bool upd = pm > mS[sd] + 8.0f;   // deferred-max (T13)
    const float nm = upd ? pm : mS[sd];
    const float sc = exp2f(mS[sd] - nm);   // ==1.0 exactly when !upd
    mS[sd] = nm;
    lS[sd] *= sc;
    if (__any(upd)) {  // redistribute sc from q=r16 layout to (g,j) layout
      #pragma unroll
      for (int j = 0; j < 4; ++j) {
        const float scj = __shfl(sc, g * 4 + j);
        #pragma unroll
        for (int nf = 0; nf < 4; ++nf) o[sd][nf][j] *= scj;
      }
    }
    // P = exp2(S-m): write each pb chunk ASAP (hides DS latency under the
    // remaining exp2s and the rs shfl chain), reduce rs after.
    float rs = 0.0f;
    #pragma unroll
    for (int ni = 0; ni < 4; ++ni) {
      bf16x4 pb;
      #pragma unroll
      for (int j = 0; j < 4; ++j) {
        const float pv = exp2f(s[ni][j] - mS[sd]);
        rs += pv;
        pb[j] = (__bf16)pv;
      }
      const int ch = 2 * ni + (g >> 1);    // row q=r16, kv-chunk, half g&1
      *(bf16x4*)&pP[wave][r16 * 64 + ((ch ^ (r16 & 7)) * 8) + (g & 1) * 4] = pb;
    }
    rs += __shfl_xor(rs, 16);
    rs += __shfl_xor(rs, 32);
    lS[sd] += rs;
  };

  const int ntiles = 32 - i;         // KV tiles needed by side B (q-tile 31-i)
  ASTAGE(0, 0);
  asm volatile("s_waitcnt vmcnt(0)" ::: "memory");
  __syncthreads();
  int cur = 0;

  for (int t = 0; t < ntiles; ++t) {
    const int kv0 = t << 6;
    if (t + 1 < ntiles) ASTAGE(cur ^ 1, kv0 + 64);  // next tile under compute

    #pragma unroll
    for (int sd = 0; sd < 2; ++sd) {
      if (sd == 0 && t > i) continue;       // side A inactive past its diagonal
      const int qw = qtile[sd] * 64 + wave * 16;

      // ---- QK^T swapped: s[ni][j] = S[kv0+ni*16+g*4+j][qw+r16] ----
      f32x4 s[4] = {};
      #pragma unroll
      for (int c = 0; c < 2; ++c) {
        bf16x8 kf[4];
        #pragma unroll
        for (int ni = 0; ni < 4; ++ni) {
          const int row = ni * 16 + r16;
          kf[ni] = *(const bf16x8*)&lK[cur][row * 64 + ((c * 4 + g) ^ (row & 7)) * 8];
        }
        __builtin_amdgcn_s_setprio(1);
        #pragma unroll
        for (int ni = 0; ni < 4; ++ni)
          s[ni] = __builtin_amdgcn_mfma_f32_16x16x32_bf16(kf[ni], qf[sd][c], s[ni], 0, 0, 0);
        __builtin_amdgcn_s_setprio(0);
      }

      // ---- causal mask (diagonal tile of this side only) ----
      if (t == ((sd == 0) ? i : (ntiles - 1))) {
        #pragma unroll
        for (int ni = 0; ni < 4; ++ni)
          #pragma unroll
          for (int j = 0; j < 4; ++j)
            if (kv0 + ni * 16 + g * 4 + j > qw + r16) s[ni][j] = -__builtin_inff();
      }

      sm_side(s, sd);
      asm volatile("s_waitcnt lgkmcnt(0)" ::: "memory");
      __builtin_amdgcn_sched_barrier(0);

      // ---- PV: O += P * V^T, 8 MFMAs ----
      __builtin_amdgcn_s_setprio(1);
      #pragma unroll
      for (int c = 0; c < 2; ++c) {
        const bf16x8 pf = *(const bf16x8*)&pP[wave][r16 * 64 + (((c * 4 + g) ^ (r16 & 7)) * 8)];
        #pragma unroll
        for (int nf = 0; nf < 4; ++nf) {
          const int row = nf * 16 + r16;
          const bf16x8 vf = *(const bf16x8*)&lV[cur][row * 64 + ((c * 4 + g) ^ (row & 7)) * 8];
          o[sd][nf] = __builtin_amdgcn_mfma_f32_16x16x32_bf16(pf, vf, o[sd][nf], 0, 0, 0);
        }
      }
      __builtin_amdgcn_s_setprio(0);
    }

    asm volatile("s_waitcnt vmcnt(0)" ::: "memory");  // next-tile loads landed
    __syncthreads();
    cur ^= 1;
  }

  // ---- epilogue -> Y[b][t][h][d] bf16 (both sides); l via shfl ----
  #pragma unroll
  for (int sd = 0; sd < 2; ++sd) {
    const int qw = qtile[sd] * 64 + wave * 16;
    #pragma unroll
    for (int j = 0; j < 4; ++j) {
      const float lq = __shfl(lS[sd], g * 4 + j);
      const float inv = 1.0f / lq;
      const int tq = qw + g * 4 + j;
      #pragma unroll
      for (int nf = 0; nf < 4; ++nf) {
        const int d = nf * 16 + r16;
        Y[(((size_t)b * T_ + tq) * NH_ + h) * HD_ + d] = (__bf16)(o[sd][nf][j] * inv);
      }
    }
  }
#undef ASTAGE
}

extern "C" void kernel_launch(void* const* d_in, const int* in_sizes, int n_in,
                              void* d_out, int out_size, void* d_ws, size_t ws_size,
                              hipStream_t stream) {
  const float* x = (const float*)d_in[0];
  const float* Wqkv = (const float*)d_in[1];
  const float* Wproj = (const float*)d_in[2];
  float* out = (float*)d_out;

  char* ws = (char*)d_ws;
  size_t off = 0;
  auto alloc = [&](size_t bytes) {
    char* p = ws + off;
    off += (bytes + 255) & ~(size_t)255;
    return p;
  };
  __bf16* xb     = (__bf16*)alloc((size_t)M_ * C_ * 2);          // 8 MB
  __bf16* wqkvT  = (__bf16*)alloc((size_t)NQKV_ * C_ * 2);       // 3 MB
  __bf16* wprojT = (__bf16*)alloc((size_t)C_ * C_ * 2);          // 2 MB
  float*  cosT   = (float*)alloc((size_t)T_ * 32 * 4);
  float*  sinT   = (float*)alloc((size_t)T_ * 32 * 4);
  float*  qkv    = (float*)alloc((size_t)M_ * NQKV_ * 4);        // 25 MB
  __bf16* Qb     = (__bf16*)alloc((size_t)B_ * NH_ * T_ * HD_ * 2);
  __bf16* Kb     = (__bf16*)alloc((size_t)B_ * NKV_ * T_ * HD_ * 2);
  __bf16* Vt     = (__bf16*)alloc((size_t)B_ * NKV_ * T_ * HD_ * 2);
  __bf16* Yb     = (__bf16*)alloc((size_t)M_ * C_ * 2);          // 8 MB

  hipLaunchKernelGGL(cast_x_kernel, dim3(M_ * C_ / 4 / 256), dim3(256), 0, stream, x, xb);
  hipLaunchKernelGGL(transpose_cast_kernel, dim3(NQKV_ / 64, C_ / 64), dim3(256), 0, stream,
                     Wqkv, wqkvT, C_, NQKV_);
  hipLaunchKernelGGL(transpose_cast_kernel, dim3(C_ / 64, C_ / 64), dim3(256), 0, stream,
                     Wproj, wprojT, C_, C_);
  hipLaunchKernelGGL(rope_table_kernel, dim3(T_ * 32 / 256), dim3(256), 0, stream, cosT, sinT);
  hipLaunchKernelGGL(gemm_tn_kernel, dim3(NQKV_ / 128, M_ / 128), dim3(256), 0, stream,
                     xb, wqkvT, qkv, NQKV_, C_);
  hipLaunchKernelGGL(rope_qk_kernel, dim3(M_ * (NH_ + NKV_) * 32 / 256), dim3(256), 0, stream,
                     qkv, cosT, sinT, Qb, Kb);
  hipLaunchKernelGGL(v_transpose_kernel, dim3(B_ * NKV_ * (T_ / 64)), dim3(256), 0, stream,
                     qkv, Vt);
  hipLaunchKernelGGL(attn_kernel, dim3(16 * B_ * NH_), dim3(256), 0, stream, Qb, Kb, Vt, Yb);
  hipLaunchKernelGGL(gemm_tn_kernel, dim3(C_ / 128, M_ / 128), dim3(256), 0, stream,
                     Yb, wprojT, out, C_, C_);
}